// Round 2
// baseline (350.180 us; speedup 1.0000x reference)
//
#include <hip/hip_runtime.h>

#define N_NODES 50000
#define N_EDGES 800000
#define F 64
#define SCAN_THREADS 1024
#define CHUNK ((N_NODES + SCAN_THREADS - 1) / SCAN_THREADS)   // 49

// ---------------------------------------------------------------------------
// GCNConv improved=True, atomic-free:
//   1) counts[dst]++                    (int atomics, 50K bins)
//   2) exclusive scan -> offsets; dinv = rsqrt(counts+2)
//   3) counting-sort edges by dst -> sorted_src
//   4) per-node wave: acc = 2*dinv^2*x[n] + sum_e dinv[s]*dinv[n]*x[s]
//      then fused @W + b, relu, log_softmax  -> single write of out
// Aggregate x BEFORE the weight transform ((A x) W == A (x W)).
// ---------------------------------------------------------------------------

__global__ void k_zero(int* __restrict__ counts) {
    int i = blockIdx.x * blockDim.x + threadIdx.x;
    if (i < N_NODES) counts[i] = 0;
}

__global__ void k_count(const int* __restrict__ dst, int* __restrict__ counts) {
    int e = blockIdx.x * blockDim.x + threadIdx.x;
    if (e < N_EDGES) atomicAdd(&counts[dst[e]], 1);
}

// single block: exclusive scan of counts -> offsets, plus dinv.
// counts array doubles as the fill-cursor (read-then-write per element).
__global__ __launch_bounds__(SCAN_THREADS) void k_scan(int* __restrict__ counts,
                                                       int* __restrict__ offsets,
                                                       float* __restrict__ dinv) {
    __shared__ int part[SCAN_THREADS];
    int t = threadIdx.x;
    int base = t * CHUNK;
    int lim = min(base + CHUNK, N_NODES);
    int sum = 0;
    for (int i = base; i < lim; ++i) sum += counts[i];
    part[t] = sum;
    __syncthreads();
    for (int off = 1; off < SCAN_THREADS; off <<= 1) {
        int v = (t >= off) ? part[t - off] : 0;
        __syncthreads();
        part[t] += v;
        __syncthreads();
    }
    int running = part[t] - sum;   // exclusive prefix of this thread's chunk
    for (int i = base; i < lim; ++i) {
        int c = counts[i];
        offsets[i] = running;
        counts[i] = running;       // becomes the fill cursor
        dinv[i] = rsqrtf((float)c + 2.0f);
        running += c;
    }
    if (t == 0) offsets[N_NODES] = N_EDGES;
}

__global__ void k_fill(const int* __restrict__ src, const int* __restrict__ dst,
                       int* __restrict__ cursor, int* __restrict__ sorted_src) {
    int e = blockIdx.x * blockDim.x + threadIdx.x;
    if (e < N_EDGES) {
        int pos = atomicAdd(&cursor[dst[e]], 1);
        sorted_src[pos] = src[e];
    }
}

// 4 nodes per 256-thread block; one wave per node; lane = feature.
__global__ __launch_bounds__(256) void k_agg(const float* __restrict__ x,
                                             const float* __restrict__ dinv,
                                             const int* __restrict__ offsets,
                                             const int* __restrict__ sorted_src,
                                             const float* __restrict__ W,
                                             const float* __restrict__ b,
                                             float* __restrict__ out) {
    __shared__ float sW[F * F];
    __shared__ float srow[4][F];
    int t = threadIdx.x;
    for (int i = t; i < F * F; i += 256) sW[i] = W[i];
    __syncthreads();

    int wid  = t >> 6;
    int lane = t & 63;
    int n = blockIdx.x * 4 + wid;            // 12500 * 4 == 50000 exactly
    float dn = dinv[n];
    float acc = 2.0f * dn * dn * x[n * F + lane];   // self loop (w=2)

    int beg = offsets[n];
    int end = offsets[n + 1];
    for (int i = beg; i < end; ++i) {
        int s = sorted_src[i];                      // wave-uniform
        acc = fmaf(dn * dinv[s], x[s * F + lane], acc);  // coalesced 256B row
    }

    srow[wid][lane] = acc;                   // wave-local LDS, no cross-wave dep

    float y = b[lane];
#pragma unroll
    for (int k = 0; k < F; ++k)
        y = fmaf(srow[wid][k], sW[k * F + lane], y);
    y = fmaxf(y, 0.0f);

    float m = y;
#pragma unroll
    for (int off = 32; off > 0; off >>= 1)
        m = fmaxf(m, __shfl_xor(m, off));
    float ex = __expf(y - m);
    float ssum = ex;
#pragma unroll
    for (int off = 32; off > 0; off >>= 1)
        ssum += __shfl_xor(ssum, off);

    out[n * F + lane] = y - m - __logf(ssum);
}

// ---------------- fallback (atomic scatter) if ws is tiny -------------------

__global__ void k_init_deg_f(float* __restrict__ deg) {
    int i = blockIdx.x * blockDim.x + threadIdx.x;
    if (i < N_NODES) deg[i] = 2.0f;
}
__global__ void k_count_f(const int* __restrict__ dst, float* __restrict__ deg) {
    int e = blockIdx.x * blockDim.x + threadIdx.x;
    if (e < N_EDGES) atomicAdd(&deg[dst[e]], 1.0f);
}
__global__ void k_dinv_f(float* __restrict__ deg) {
    int i = blockIdx.x * blockDim.x + threadIdx.x;
    if (i < N_NODES) deg[i] = rsqrtf(deg[i]);
}
__global__ void k_selfinit_f(const float* __restrict__ x, const float* __restrict__ dinv,
                             float* __restrict__ agg) {
    int t = blockIdx.x * blockDim.x + threadIdx.x;
    if (t >= N_NODES * (F / 4)) return;
    int n = t >> 4;
    float d = dinv[n];
    float c = 2.0f * d * d;
    float4 v = reinterpret_cast<const float4*>(x)[t];
    float4 o; o.x = c*v.x; o.y = c*v.y; o.z = c*v.z; o.w = c*v.w;
    reinterpret_cast<float4*>(agg)[t] = o;
}
__global__ __launch_bounds__(256) void k_scatter_f(const int* __restrict__ src,
                                                   const int* __restrict__ dst,
                                                   const float* __restrict__ x,
                                                   const float* __restrict__ dinv,
                                                   float* __restrict__ agg) {
    int wave = (blockIdx.x * blockDim.x + threadIdx.x) >> 6;
    int lane = threadIdx.x & 63;
    if (wave >= N_EDGES) return;
    int s = src[wave], d = dst[wave];
    float c = dinv[s] * dinv[d];
    atomicAdd(&agg[d * F + lane], c * x[s * F + lane]);
}
__global__ __launch_bounds__(256) void k_final_f(const float* __restrict__ W,
                                                 const float* __restrict__ b,
                                                 float* __restrict__ out) {
    __shared__ float sW[F * F];
    __shared__ float srow[4][F];
    int t = threadIdx.x;
    for (int i = t; i < F * F; i += 256) sW[i] = W[i];
    int wid = t >> 6, lane = t & 63;
    int n = blockIdx.x * 4 + wid;
    float rv = out[n * F + lane];
    srow[wid][lane] = rv;
    __syncthreads();
    float y = b[lane];
#pragma unroll
    for (int k = 0; k < F; ++k) y = fmaf(srow[wid][k], sW[k * F + lane], y);
    y = fmaxf(y, 0.0f);
    float m = y;
#pragma unroll
    for (int off = 32; off > 0; off >>= 1) m = fmaxf(m, __shfl_xor(m, off));
    float ex = __expf(y - m);
    float ssum = ex;
#pragma unroll
    for (int off = 32; off > 0; off >>= 1) ssum += __shfl_xor(ssum, off);
    out[n * F + lane] = y - m - __logf(ssum);
}

// ---------------------------------------------------------------------------

extern "C" void kernel_launch(void* const* d_in, const int* in_sizes, int n_in,
                              void* d_out, int out_size, void* d_ws, size_t ws_size,
                              hipStream_t stream) {
    const float* x    = (const float*)d_in[0];
    const int*   eidx = (const int*)d_in[1];   // [2][E]: row0 = src, row1 = dst
    const float* W    = (const float*)d_in[2];
    const float* b    = (const float*)d_in[3];
    const int* src = eidx;
    const int* dst = eidx + N_EDGES;
    float* out = (float*)d_out;

    // ws layout (byte offsets, 16B aligned):
    //   counts/cursor: [0, 200000)
    //   offsets:       [200000, 400004)  (pad to 400016)
    //   dinv:          [400016, 600016)
    //   sorted_src:    [600016, 3800016)
    const size_t NEED = 3800016;

    if (ws_size >= NEED) {
        char* ws = (char*)d_ws;
        int*   counts     = (int*)(ws);
        int*   offsets    = (int*)(ws + 200000);
        float* dinv       = (float*)(ws + 400016);
        int*   sorted_src = (int*)(ws + 600016);

        k_zero<<<(N_NODES + 255) / 256, 256, 0, stream>>>(counts);
        k_count<<<(N_EDGES + 255) / 256, 256, 0, stream>>>(dst, counts);
        k_scan<<<1, SCAN_THREADS, 0, stream>>>(counts, offsets, dinv);
        k_fill<<<(N_EDGES + 255) / 256, 256, 0, stream>>>(src, dst, counts, sorted_src);
        k_agg<<<N_NODES / 4, 256, 0, stream>>>(x, dinv, offsets, sorted_src, W, b, out);
    } else {
        float* deg = (float*)d_ws;
        k_init_deg_f<<<(N_NODES + 255) / 256, 256, 0, stream>>>(deg);
        k_count_f<<<(N_EDGES + 255) / 256, 256, 0, stream>>>(dst, deg);
        k_dinv_f<<<(N_NODES + 255) / 256, 256, 0, stream>>>(deg);
        k_selfinit_f<<<(N_NODES * (F / 4) + 255) / 256, 256, 0, stream>>>(x, deg, out);
        k_scatter_f<<<(N_EDGES * 64 + 255) / 256, 256, 0, stream>>>(src, dst, x, deg, out);
        k_final_f<<<N_NODES / 4, 256, 0, stream>>>(W, b, out);
    }
}

// Round 3
// 161.727 us; speedup vs baseline: 2.1653x; 2.1653x over previous
//
#include <hip/hip_runtime.h>

#define N_NODES 50000
#define N_EDGES 800000
#define F 64
#define NB ((N_NODES + 255) / 256)   // 196 scan blocks

// ---------------------------------------------------------------------------
// GCNConv improved=True, atomic-free aggregation:
//   1) counts[dst]++                         (int atomics, 50K bins)
//   2) 3-phase parallel exclusive scan -> offsets/cursor; dinv = rsqrt(c+2)
//   3) counting-sort fill: sorted_src + norm (= dinv[s]*dinv[d]) per slot
//   4) per-node wave: 4 edges in parallel (16 lanes x float4 each),
//      shfl_xor reduce, + self loop, fused @W + b, relu, log_softmax.
// Aggregate x BEFORE the weight transform ((A x) W == A (x W)).
// ---------------------------------------------------------------------------

__global__ void k_count(const int* __restrict__ dst, int* __restrict__ counts) {
    int e = blockIdx.x * blockDim.x + threadIdx.x;
    if (e < N_EDGES) atomicAdd(&counts[dst[e]], 1);
}

__global__ __launch_bounds__(256) void k_blocksum(const int* __restrict__ counts,
                                                  int* __restrict__ bs) {
    __shared__ int sh[256];
    int t = threadIdx.x;
    int g = blockIdx.x * 256 + t;
    int v = (g < N_NODES) ? counts[g] : 0;
    sh[t] = v;
    __syncthreads();
    for (int off = 128; off > 0; off >>= 1) {
        if (t < off) sh[t] += sh[t + off];
        __syncthreads();
    }
    if (t == 0) bs[blockIdx.x] = sh[0];
}

__global__ __launch_bounds__(256) void k_scanblocks(int* __restrict__ bs) {
    __shared__ int sh[256];
    int t = threadIdx.x;
    int v = (t < NB) ? bs[t] : 0;
    sh[t] = v;
    __syncthreads();
    for (int off = 1; off < 256; off <<= 1) {
        int u = (t >= off) ? sh[t - off] : 0;
        __syncthreads();
        sh[t] += u;
        __syncthreads();
    }
    if (t < NB) bs[t] = sh[t] - v;   // exclusive prefix of block sums
}

// local exclusive scan + global offset; counts becomes the fill cursor.
__global__ __launch_bounds__(256) void k_offsets(int* __restrict__ counts,
                                                 const int* __restrict__ bs,
                                                 int* __restrict__ offsets,
                                                 float* __restrict__ dinv) {
    __shared__ int sh[256];
    int t = threadIdx.x;
    int g = blockIdx.x * 256 + t;
    int c = (g < N_NODES) ? counts[g] : 0;
    sh[t] = c;
    __syncthreads();
    for (int off = 1; off < 256; off <<= 1) {
        int u = (t >= off) ? sh[t - off] : 0;
        __syncthreads();
        sh[t] += u;
        __syncthreads();
    }
    int excl = sh[t] - c + bs[blockIdx.x];
    if (g < N_NODES) {
        offsets[g] = excl;
        counts[g]  = excl;                       // fill cursor
        dinv[g]    = rsqrtf((float)c + 2.0f);
    }
    if (g == 0) offsets[N_NODES] = N_EDGES;
}

template <bool HN>
__global__ void k_fill(const int* __restrict__ src, const int* __restrict__ dst,
                       const float* __restrict__ dinv, int* __restrict__ cursor,
                       int* __restrict__ sorted_src, float* __restrict__ norm_sorted) {
    int e = blockIdx.x * blockDim.x + threadIdx.x;
    if (e < N_EDGES) {
        int d = dst[e], s = src[e];
        int pos = atomicAdd(&cursor[d], 1);
        sorted_src[pos] = s;
        if (HN) norm_sorted[pos] = dinv[s] * dinv[d];
    }
}

// 4 nodes per 256-thread block; one wave per node.
// Within a wave: qe = lane>>4 picks 1 of 4 parallel edges, qc = lane&15 picks
// the float4 chunk of the 64-float row. shfl_xor(16,32) reduces edge groups.
template <bool HN>
__global__ __launch_bounds__(256) void k_agg(const float* __restrict__ x,
                                             const float* __restrict__ dinv,
                                             const int* __restrict__ offsets,
                                             const int* __restrict__ sorted_src,
                                             const float* __restrict__ norm_sorted,
                                             const float* __restrict__ W,
                                             const float* __restrict__ b,
                                             float* __restrict__ out) {
    __shared__ float sW[F * F];
    __shared__ float srow[4][F];
    int t = threadIdx.x;
    for (int i = t; i < F * F; i += 256) sW[i] = W[i];

    int wid = t >> 6, lane = t & 63;
    int n = blockIdx.x * 4 + wid;            // 12500 * 4 == 50000 exactly
    int qe = lane >> 4, qc = lane & 15;
    float dn = dinv[n];

    int beg = offsets[n], end = offsets[n + 1];
    float4 acc = make_float4(0.f, 0.f, 0.f, 0.f);
    int base = beg;
    for (; base + 8 <= end; base += 8) {     // 8 edges per iter, 2 loads in flight
        int e0 = base + qe, e1 = base + 4 + qe;
        int s0 = sorted_src[e0];
        int s1 = sorted_src[e1];
        float nm0 = HN ? norm_sorted[e0] : dn * dinv[s0];
        float nm1 = HN ? norm_sorted[e1] : dn * dinv[s1];
        float4 v0 = reinterpret_cast<const float4*>(x + (size_t)s0 * F)[qc];
        float4 v1 = reinterpret_cast<const float4*>(x + (size_t)s1 * F)[qc];
        acc.x = fmaf(nm0, v0.x, acc.x); acc.y = fmaf(nm0, v0.y, acc.y);
        acc.z = fmaf(nm0, v0.z, acc.z); acc.w = fmaf(nm0, v0.w, acc.w);
        acc.x = fmaf(nm1, v1.x, acc.x); acc.y = fmaf(nm1, v1.y, acc.y);
        acc.z = fmaf(nm1, v1.z, acc.z); acc.w = fmaf(nm1, v1.w, acc.w);
    }
    for (; base < end; base += 4) {          // tail, predicated
        int e = base + qe;
        int s = n; float nm = 0.f;
        if (e < end) {
            s = sorted_src[e];
            nm = HN ? norm_sorted[e] : dn * dinv[s];
        }
        float4 v = reinterpret_cast<const float4*>(x + (size_t)s * F)[qc];
        acc.x = fmaf(nm, v.x, acc.x); acc.y = fmaf(nm, v.y, acc.y);
        acc.z = fmaf(nm, v.z, acc.z); acc.w = fmaf(nm, v.w, acc.w);
    }
    // reduce across the 4 edge groups (lanes differing in bits 4,5)
    acc.x += __shfl_xor(acc.x, 16); acc.y += __shfl_xor(acc.y, 16);
    acc.z += __shfl_xor(acc.z, 16); acc.w += __shfl_xor(acc.w, 16);
    acc.x += __shfl_xor(acc.x, 32); acc.y += __shfl_xor(acc.y, 32);
    acc.z += __shfl_xor(acc.z, 32); acc.w += __shfl_xor(acc.w, 32);
    // self loop (weight 2)
    float c2 = 2.0f * dn * dn;
    float4 xv = reinterpret_cast<const float4*>(x + (size_t)n * F)[qc];
    acc.x = fmaf(c2, xv.x, acc.x); acc.y = fmaf(c2, xv.y, acc.y);
    acc.z = fmaf(c2, xv.z, acc.z); acc.w = fmaf(c2, xv.w, acc.w);

    if (qe == 0) reinterpret_cast<float4*>(&srow[wid][0])[qc] = acc;
    __syncthreads();                          // also covers sW staging

    float y = b[lane];
#pragma unroll
    for (int k = 0; k < F; ++k)
        y = fmaf(srow[wid][k], sW[k * F + lane], y);
    y = fmaxf(y, 0.0f);

    float mx = y;
#pragma unroll
    for (int off = 32; off > 0; off >>= 1)
        mx = fmaxf(mx, __shfl_xor(mx, off));
    float ex = __expf(y - mx);
    float ss = ex;
#pragma unroll
    for (int off = 32; off > 0; off >>= 1)
        ss += __shfl_xor(ss, off);

    out[n * F + lane] = y - mx - __logf(ss);
}

// ---------------- fallback (atomic scatter, round-0 proven) -----------------

__global__ void k_init_deg_f(float* __restrict__ deg) {
    int i = blockIdx.x * blockDim.x + threadIdx.x;
    if (i < N_NODES) deg[i] = 2.0f;
}
__global__ void k_count_f(const int* __restrict__ dst, float* __restrict__ deg) {
    int e = blockIdx.x * blockDim.x + threadIdx.x;
    if (e < N_EDGES) atomicAdd(&deg[dst[e]], 1.0f);
}
__global__ void k_dinv_f(float* __restrict__ deg) {
    int i = blockIdx.x * blockDim.x + threadIdx.x;
    if (i < N_NODES) deg[i] = rsqrtf(deg[i]);
}
__global__ void k_selfinit_f(const float* __restrict__ x, const float* __restrict__ dinv,
                             float* __restrict__ agg) {
    int t = blockIdx.x * blockDim.x + threadIdx.x;
    if (t >= N_NODES * (F / 4)) return;
    int n = t >> 4;
    float d = dinv[n];
    float c = 2.0f * d * d;
    float4 v = reinterpret_cast<const float4*>(x)[t];
    float4 o; o.x = c*v.x; o.y = c*v.y; o.z = c*v.z; o.w = c*v.w;
    reinterpret_cast<float4*>(agg)[t] = o;
}
__global__ __launch_bounds__(256) void k_scatter_f(const int* __restrict__ src,
                                                   const int* __restrict__ dst,
                                                   const float* __restrict__ x,
                                                   const float* __restrict__ dinv,
                                                   float* __restrict__ agg) {
    int wave = (blockIdx.x * blockDim.x + threadIdx.x) >> 6;
    int lane = threadIdx.x & 63;
    if (wave >= N_EDGES) return;
    int s = src[wave], d = dst[wave];
    atomicAdd(&agg[d * F + lane], dinv[s] * dinv[d] * x[s * F + lane]);
}
__global__ __launch_bounds__(256) void k_final_f(const float* __restrict__ W,
                                                 const float* __restrict__ b,
                                                 float* __restrict__ out) {
    __shared__ float sW[F * F];
    __shared__ float srow[4][F];
    int t = threadIdx.x;
    for (int i = t; i < F * F; i += 256) sW[i] = W[i];
    int wid = t >> 6, lane = t & 63;
    int n = blockIdx.x * 4 + wid;
    float rv = out[n * F + lane];
    srow[wid][lane] = rv;
    __syncthreads();
    float y = b[lane];
#pragma unroll
    for (int k = 0; k < F; ++k) y = fmaf(srow[wid][k], sW[k * F + lane], y);
    y = fmaxf(y, 0.0f);
    float m = y;
#pragma unroll
    for (int off = 32; off > 0; off >>= 1) m = fmaxf(m, __shfl_xor(m, off));
    float ex = __expf(y - m);
    float ss = ex;
#pragma unroll
    for (int off = 32; off > 0; off >>= 1) ss += __shfl_xor(ss, off);
    out[n * F + lane] = y - m - __logf(ss);
}

// ---------------------------------------------------------------------------

extern "C" void kernel_launch(void* const* d_in, const int* in_sizes, int n_in,
                              void* d_out, int out_size, void* d_ws, size_t ws_size,
                              hipStream_t stream) {
    const float* x    = (const float*)d_in[0];
    const int*   eidx = (const int*)d_in[1];   // [2][E]: row0 = src, row1 = dst
    const float* W    = (const float*)d_in[2];
    const float* b    = (const float*)d_in[3];
    const int* src = eidx;
    const int* dst = eidx + N_EDGES;
    float* out = (float*)d_out;

    // ws layout (byte offsets, 16B aligned):
    //   counts/cursor [0, 200000)
    //   offsets       [200000, 400004) pad->400016
    //   dinv          [400016, 600016)
    //   blocksums     [600016, 601040)
    //   sorted_src    [601040, 3801040)
    //   norm_sorted   [3801040, 7001040)      (optional)
    const size_t NEED_MID  = 3801040;
    const size_t NEED_FULL = 7001040;

    if (ws_size >= NEED_MID) {
        char* ws = (char*)d_ws;
        int*   counts     = (int*)(ws);
        int*   offsets    = (int*)(ws + 200000);
        float* dinv       = (float*)(ws + 400016);
        int*   bs         = (int*)(ws + 600016);
        int*   sorted_src = (int*)(ws + 601040);
        float* norm_sorted = (float*)(ws + 3801040);
        bool full = (ws_size >= NEED_FULL);

        hipMemsetAsync(counts, 0, N_NODES * sizeof(int), stream);
        k_count<<<(N_EDGES + 255) / 256, 256, 0, stream>>>(dst, counts);
        k_blocksum<<<NB, 256, 0, stream>>>(counts, bs);
        k_scanblocks<<<1, 256, 0, stream>>>(bs);
        k_offsets<<<NB, 256, 0, stream>>>(counts, bs, offsets, dinv);
        if (full) {
            k_fill<true><<<(N_EDGES + 255) / 256, 256, 0, stream>>>(
                src, dst, dinv, counts, sorted_src, norm_sorted);
            k_agg<true><<<N_NODES / 4, 256, 0, stream>>>(
                x, dinv, offsets, sorted_src, norm_sorted, W, b, out);
        } else {
            k_fill<false><<<(N_EDGES + 255) / 256, 256, 0, stream>>>(
                src, dst, dinv, counts, sorted_src, nullptr);
            k_agg<false><<<N_NODES / 4, 256, 0, stream>>>(
                x, dinv, offsets, sorted_src, nullptr, W, b, out);
        }
    } else {
        float* deg = (float*)d_ws;
        k_init_deg_f<<<(N_NODES + 255) / 256, 256, 0, stream>>>(deg);
        k_count_f<<<(N_EDGES + 255) / 256, 256, 0, stream>>>(dst, deg);
        k_dinv_f<<<(N_NODES + 255) / 256, 256, 0, stream>>>(deg);
        k_selfinit_f<<<(N_NODES * (F / 4) + 255) / 256, 256, 0, stream>>>(x, deg, out);
        k_scatter_f<<<(N_EDGES * 64 + 255) / 256, 256, 0, stream>>>(src, dst, x, deg, out);
        k_final_f<<<N_NODES / 4, 256, 0, stream>>>(W, b, out);
    }
}

// Round 4
// 148.800 us; speedup vs baseline: 2.3534x; 1.0869x over previous
//
#include <hip/hip_runtime.h>
#include <hip/hip_fp16.h>

#define N_NODES 50000
#define N_EDGES 800000
#define F 64
#define NB ((N_NODES + 255) / 256)   // 196 scan blocks

// ---------------------------------------------------------------------------
// GCNConv improved=True, atomic-free aggregation:
//   1) counts[dst]++  fused with  xh = fp16(x)      (same 3125x256 grid)
//   2) 3-phase parallel exclusive scan -> offsets/cursor; dinv = rsqrt(c+2)
//   3) counting-sort fill: ONE 8B store per edge {src, norm}
//   4) per-node wave: 16 fp16 rows in flight (8 groups x 8 lanes x 16B,
//      unroll 2), shfl_xor(8,16,32) reduce, self loop from f32 x,
//      fused @W + b, relu, log_softmax.
// Aggregate x BEFORE the weight transform ((A x) W == A (x W)).
// ---------------------------------------------------------------------------

union H2U { __half2 h; unsigned u; };

__global__ __launch_bounds__(256) void k_count_convert(const int* __restrict__ dst,
                                                       int* __restrict__ counts,
                                                       const float4* __restrict__ x4,
                                                       uint2* __restrict__ xh8) {
    int t = blockIdx.x * 256 + threadIdx.x;   // 3125*256 == 800000 == N_EDGES == N*F/4
    atomicAdd(&counts[dst[t]], 1);
    float4 v = x4[t];
    H2U a, b;
    a.h = __float22half2_rn(make_float2(v.x, v.y));
    b.h = __float22half2_rn(make_float2(v.z, v.w));
    uint2 o; o.x = a.u; o.y = b.u;
    xh8[t] = o;
}

__global__ __launch_bounds__(256) void k_blocksum(const int* __restrict__ counts,
                                                  int* __restrict__ bs) {
    __shared__ int sh[256];
    int t = threadIdx.x;
    int g = blockIdx.x * 256 + t;
    int v = (g < N_NODES) ? counts[g] : 0;
    sh[t] = v;
    __syncthreads();
    for (int off = 128; off > 0; off >>= 1) {
        if (t < off) sh[t] += sh[t + off];
        __syncthreads();
    }
    if (t == 0) bs[blockIdx.x] = sh[0];
}

__global__ __launch_bounds__(256) void k_scanblocks(int* __restrict__ bs) {
    __shared__ int sh[256];
    int t = threadIdx.x;
    int v = (t < NB) ? bs[t] : 0;
    sh[t] = v;
    __syncthreads();
    for (int off = 1; off < 256; off <<= 1) {
        int u = (t >= off) ? sh[t - off] : 0;
        __syncthreads();
        sh[t] += u;
        __syncthreads();
    }
    if (t < NB) bs[t] = sh[t] - v;   // exclusive prefix of block sums
}

__global__ __launch_bounds__(256) void k_offsets(int* __restrict__ counts,
                                                 const int* __restrict__ bs,
                                                 int* __restrict__ offsets,
                                                 float* __restrict__ dinv) {
    __shared__ int sh[256];
    int t = threadIdx.x;
    int g = blockIdx.x * 256 + t;
    int c = (g < N_NODES) ? counts[g] : 0;
    sh[t] = c;
    __syncthreads();
    for (int off = 1; off < 256; off <<= 1) {
        int u = (t >= off) ? sh[t - off] : 0;
        __syncthreads();
        sh[t] += u;
        __syncthreads();
    }
    int excl = sh[t] - c + bs[blockIdx.x];
    if (g < N_NODES) {
        offsets[g] = excl;
        counts[g]  = excl;                       // fill cursor
        dinv[g]    = rsqrtf((float)c + 2.0f);
    }
    if (g == 0) offsets[N_NODES] = N_EDGES;
}

__global__ __launch_bounds__(256) void k_fill(const int* __restrict__ src,
                                              const int* __restrict__ dst,
                                              const float* __restrict__ dinv,
                                              int* __restrict__ cursor,
                                              int2* __restrict__ pack) {
    int e = blockIdx.x * 256 + threadIdx.x;
    if (e < N_EDGES) {
        int d = dst[e], s = src[e];
        int pos = atomicAdd(&cursor[d], 1);
        float nm = dinv[s] * dinv[d];
        int2 v; v.x = s; v.y = __float_as_int(nm);
        pack[pos] = v;                           // single 8B scattered store
    }
}

// 4 nodes per 256-thread block; one wave per node.
// qe = lane>>3 picks 1 of 8 parallel edges; qc = lane&7 picks the 16B (8-half)
// chunk of the 128B fp16 row. shfl_xor(8,16,32) reduces the 8 edge groups.
__global__ __launch_bounds__(256) void k_agg(const float* __restrict__ x,
                                             const __half* __restrict__ xh,
                                             const float* __restrict__ dinv,
                                             const int* __restrict__ offsets,
                                             const int2* __restrict__ pack,
                                             const float* __restrict__ W,
                                             const float* __restrict__ b,
                                             float* __restrict__ out) {
    __shared__ float sW[F * F];
    __shared__ float srow[4][F];
    int t = threadIdx.x;
    {   // vectorized W staging
        const float4* W4 = reinterpret_cast<const float4*>(W);
        float4* sW4 = reinterpret_cast<float4*>(sW);
        for (int i = t; i < F * F / 4; i += 256) sW4[i] = W4[i];
    }

    int wid = t >> 6, lane = t & 63;
    int n = blockIdx.x * 4 + wid;            // 12500 * 4 == 50000 exactly
    int qe = lane >> 3, qc = lane & 7;
    float dn = dinv[n];

    int beg = offsets[n], end = offsets[n + 1];
    float acc[8];
#pragma unroll
    for (int i = 0; i < 8; ++i) acc[i] = 0.f;

    const uint4* xh16 = reinterpret_cast<const uint4*>(xh);

    int base = beg;
    for (; base + 16 <= end; base += 16) {   // 16 rows in flight per wave
        int2 p0 = pack[base + qe];
        int2 p1 = pack[base + 8 + qe];
        uint4 r0 = xh16[(size_t)p0.x * (F / 8) + qc];
        uint4 r1 = xh16[(size_t)p1.x * (F / 8) + qc];
        float nm0 = __int_as_float(p0.y);
        float nm1 = __int_as_float(p1.y);
        H2U u0, u1, u2, u3;
        u0.u = r0.x; u1.u = r0.y; u2.u = r0.z; u3.u = r0.w;
        float2 f;
        f = __half22float2(u0.h); acc[0] = fmaf(nm0, f.x, acc[0]); acc[1] = fmaf(nm0, f.y, acc[1]);
        f = __half22float2(u1.h); acc[2] = fmaf(nm0, f.x, acc[2]); acc[3] = fmaf(nm0, f.y, acc[3]);
        f = __half22float2(u2.h); acc[4] = fmaf(nm0, f.x, acc[4]); acc[5] = fmaf(nm0, f.y, acc[5]);
        f = __half22float2(u3.h); acc[6] = fmaf(nm0, f.x, acc[6]); acc[7] = fmaf(nm0, f.y, acc[7]);
        u0.u = r1.x; u1.u = r1.y; u2.u = r1.z; u3.u = r1.w;
        f = __half22float2(u0.h); acc[0] = fmaf(nm1, f.x, acc[0]); acc[1] = fmaf(nm1, f.y, acc[1]);
        f = __half22float2(u1.h); acc[2] = fmaf(nm1, f.x, acc[2]); acc[3] = fmaf(nm1, f.y, acc[3]);
        f = __half22float2(u2.h); acc[4] = fmaf(nm1, f.x, acc[4]); acc[5] = fmaf(nm1, f.y, acc[5]);
        f = __half22float2(u3.h); acc[6] = fmaf(nm1, f.x, acc[6]); acc[7] = fmaf(nm1, f.y, acc[7]);
    }
    for (; base < end; base += 8) {          // tail, predicated (no divergence)
        int e = base + qe;
        int ec = min(e, end - 1);
        int2 p = pack[ec];
        float nm = (e < end) ? __int_as_float(p.y) : 0.f;
        uint4 r = xh16[(size_t)p.x * (F / 8) + qc];
        H2U u0, u1, u2, u3;
        u0.u = r.x; u1.u = r.y; u2.u = r.z; u3.u = r.w;
        float2 f;
        f = __half22float2(u0.h); acc[0] = fmaf(nm, f.x, acc[0]); acc[1] = fmaf(nm, f.y, acc[1]);
        f = __half22float2(u1.h); acc[2] = fmaf(nm, f.x, acc[2]); acc[3] = fmaf(nm, f.y, acc[3]);
        f = __half22float2(u2.h); acc[4] = fmaf(nm, f.x, acc[4]); acc[5] = fmaf(nm, f.y, acc[5]);
        f = __half22float2(u3.h); acc[6] = fmaf(nm, f.x, acc[6]); acc[7] = fmaf(nm, f.y, acc[7]);
    }

    // reduce across the 8 edge groups (lane bits 3,4,5)
#pragma unroll
    for (int i = 0; i < 8; ++i) {
        acc[i] += __shfl_xor(acc[i], 8);
        acc[i] += __shfl_xor(acc[i], 16);
        acc[i] += __shfl_xor(acc[i], 32);
    }

    // self loop (weight 2), from f32 x for precision
    float c2 = 2.0f * dn * dn;
    const float4* xn = reinterpret_cast<const float4*>(x + (size_t)n * F);
    float4 s0 = xn[qc * 2], s1 = xn[qc * 2 + 1];
    acc[0] = fmaf(c2, s0.x, acc[0]); acc[1] = fmaf(c2, s0.y, acc[1]);
    acc[2] = fmaf(c2, s0.z, acc[2]); acc[3] = fmaf(c2, s0.w, acc[3]);
    acc[4] = fmaf(c2, s1.x, acc[4]); acc[5] = fmaf(c2, s1.y, acc[5]);
    acc[6] = fmaf(c2, s1.z, acc[6]); acc[7] = fmaf(c2, s1.w, acc[7]);

    if (qe == 0) {
        float4* dstp = reinterpret_cast<float4*>(&srow[wid][qc * 8]);
        float4 w0, w1;
        w0.x = acc[0]; w0.y = acc[1]; w0.z = acc[2]; w0.w = acc[3];
        w1.x = acc[4]; w1.y = acc[5]; w1.z = acc[6]; w1.w = acc[7];
        dstp[0] = w0; dstp[1] = w1;
    }
    __syncthreads();                          // also covers sW staging

    float y = b[lane];
#pragma unroll
    for (int k = 0; k < F; ++k)
        y = fmaf(srow[wid][k], sW[k * F + lane], y);
    y = fmaxf(y, 0.0f);

    float mx = y;
#pragma unroll
    for (int off = 32; off > 0; off >>= 1)
        mx = fmaxf(mx, __shfl_xor(mx, off));
    float ex = __expf(y - mx);
    float ss = ex;
#pragma unroll
    for (int off = 32; off > 0; off >>= 1)
        ss += __shfl_xor(ss, off);

    out[n * F + lane] = y - mx - __logf(ss);
}

// ---------------- tier-B fallback (round-3 f32 path, no norm array) ---------

__global__ void k_count_b(const int* __restrict__ dst, int* __restrict__ counts) {
    int e = blockIdx.x * blockDim.x + threadIdx.x;
    if (e < N_EDGES) atomicAdd(&counts[dst[e]], 1);
}
__global__ void k_fill_b(const int* __restrict__ src, const int* __restrict__ dst,
                         int* __restrict__ cursor, int* __restrict__ sorted_src) {
    int e = blockIdx.x * blockDim.x + threadIdx.x;
    if (e < N_EDGES) {
        int pos = atomicAdd(&cursor[dst[e]], 1);
        sorted_src[pos] = src[e];
    }
}
__global__ __launch_bounds__(256) void k_agg_b(const float* __restrict__ x,
                                               const float* __restrict__ dinv,
                                               const int* __restrict__ offsets,
                                               const int* __restrict__ sorted_src,
                                               const float* __restrict__ W,
                                               const float* __restrict__ b,
                                               float* __restrict__ out) {
    __shared__ float sW[F * F];
    __shared__ float srow[4][F];
    int t = threadIdx.x;
    for (int i = t; i < F * F; i += 256) sW[i] = W[i];
    int wid = t >> 6, lane = t & 63;
    int n = blockIdx.x * 4 + wid;
    int qe = lane >> 4, qc = lane & 15;
    float dn = dinv[n];
    int beg = offsets[n], end = offsets[n + 1];
    float4 acc = make_float4(0.f, 0.f, 0.f, 0.f);
    for (int base = beg; base < end; base += 4) {
        int e = base + qe;
        int s = n; float nm = 0.f;
        if (e < end) { s = sorted_src[e]; nm = dn * dinv[s]; }
        float4 v = reinterpret_cast<const float4*>(x + (size_t)s * F)[qc];
        acc.x = fmaf(nm, v.x, acc.x); acc.y = fmaf(nm, v.y, acc.y);
        acc.z = fmaf(nm, v.z, acc.z); acc.w = fmaf(nm, v.w, acc.w);
    }
    acc.x += __shfl_xor(acc.x, 16); acc.y += __shfl_xor(acc.y, 16);
    acc.z += __shfl_xor(acc.z, 16); acc.w += __shfl_xor(acc.w, 16);
    acc.x += __shfl_xor(acc.x, 32); acc.y += __shfl_xor(acc.y, 32);
    acc.z += __shfl_xor(acc.z, 32); acc.w += __shfl_xor(acc.w, 32);
    float c2 = 2.0f * dn * dn;
    float4 xv = reinterpret_cast<const float4*>(x + (size_t)n * F)[qc];
    acc.x = fmaf(c2, xv.x, acc.x); acc.y = fmaf(c2, xv.y, acc.y);
    acc.z = fmaf(c2, xv.z, acc.z); acc.w = fmaf(c2, xv.w, acc.w);
    if (qe == 0) reinterpret_cast<float4*>(&srow[wid][0])[qc] = acc;
    __syncthreads();
    float y = b[lane];
#pragma unroll
    for (int k = 0; k < F; ++k) y = fmaf(srow[wid][k], sW[k * F + lane], y);
    y = fmaxf(y, 0.0f);
    float m = y;
#pragma unroll
    for (int off = 32; off > 0; off >>= 1) m = fmaxf(m, __shfl_xor(m, off));
    float ex = __expf(y - m);
    float ss = ex;
#pragma unroll
    for (int off = 32; off > 0; off >>= 1) ss += __shfl_xor(ss, off);
    out[n * F + lane] = y - m - __logf(ss);
}

// ---------------- tier-C fallback (atomic scatter, round-0 proven) ----------

__global__ void k_init_deg_f(float* __restrict__ deg) {
    int i = blockIdx.x * blockDim.x + threadIdx.x;
    if (i < N_NODES) deg[i] = 2.0f;
}
__global__ void k_count_f(const int* __restrict__ dst, float* __restrict__ deg) {
    int e = blockIdx.x * blockDim.x + threadIdx.x;
    if (e < N_EDGES) atomicAdd(&deg[dst[e]], 1.0f);
}
__global__ void k_dinv_f(float* __restrict__ deg) {
    int i = blockIdx.x * blockDim.x + threadIdx.x;
    if (i < N_NODES) deg[i] = rsqrtf(deg[i]);
}
__global__ void k_selfinit_f(const float* __restrict__ x, const float* __restrict__ dinv,
                             float* __restrict__ agg) {
    int t = blockIdx.x * blockDim.x + threadIdx.x;
    if (t >= N_NODES * (F / 4)) return;
    int n = t >> 4;
    float d = dinv[n];
    float c = 2.0f * d * d;
    float4 v = reinterpret_cast<const float4*>(x)[t];
    float4 o; o.x = c*v.x; o.y = c*v.y; o.z = c*v.z; o.w = c*v.w;
    reinterpret_cast<float4*>(agg)[t] = o;
}
__global__ __launch_bounds__(256) void k_scatter_f(const int* __restrict__ src,
                                                   const int* __restrict__ dst,
                                                   const float* __restrict__ x,
                                                   const float* __restrict__ dinv,
                                                   float* __restrict__ agg) {
    int wave = (blockIdx.x * blockDim.x + threadIdx.x) >> 6;
    int lane = threadIdx.x & 63;
    if (wave >= N_EDGES) return;
    int s = src[wave], d = dst[wave];
    atomicAdd(&agg[d * F + lane], dinv[s] * dinv[d] * x[s * F + lane]);
}
__global__ __launch_bounds__(256) void k_final_f(const float* __restrict__ W,
                                                 const float* __restrict__ b,
                                                 float* __restrict__ out) {
    __shared__ float sW[F * F];
    __shared__ float srow[4][F];
    int t = threadIdx.x;
    for (int i = t; i < F * F; i += 256) sW[i] = W[i];
    int wid = t >> 6, lane = t & 63;
    int n = blockIdx.x * 4 + wid;
    float rv = out[n * F + lane];
    srow[wid][lane] = rv;
    __syncthreads();
    float y = b[lane];
#pragma unroll
    for (int k = 0; k < F; ++k) y = fmaf(srow[wid][k], sW[k * F + lane], y);
    y = fmaxf(y, 0.0f);
    float m = y;
#pragma unroll
    for (int off = 32; off > 0; off >>= 1) m = fmaxf(m, __shfl_xor(m, off));
    float ex = __expf(y - m);
    float ss = ex;
#pragma unroll
    for (int off = 32; off > 0; off >>= 1) ss += __shfl_xor(ss, off);
    out[n * F + lane] = y - m - __logf(ss);
}

// ---------------------------------------------------------------------------

extern "C" void kernel_launch(void* const* d_in, const int* in_sizes, int n_in,
                              void* d_out, int out_size, void* d_ws, size_t ws_size,
                              hipStream_t stream) {
    const float* x    = (const float*)d_in[0];
    const int*   eidx = (const int*)d_in[1];   // [2][E]: row0 = src, row1 = dst
    const float* W    = (const float*)d_in[2];
    const float* b    = (const float*)d_in[3];
    const int* src = eidx;
    const int* dst = eidx + N_EDGES;
    float* out = (float*)d_out;

    // Tier-A ws layout (byte offsets):
    //   counts/cursor [0,        200000)  pad -> 200064
    //   offsets       [200064,   400068)  pad -> 400128
    //   dinv          [400128,   600128)
    //   blocksums     [600128,   601152)
    //   pack (int2)   [601152,   7001152)
    //   xh  (half)    [7001152, 13401152)
    const size_t NEED_A = 13401152;
    const size_t NEED_B = 3801040;

    if (ws_size >= NEED_A) {
        char* ws = (char*)d_ws;
        int*    counts  = (int*)(ws);
        int*    offsets = (int*)(ws + 200064);
        float*  dinv    = (float*)(ws + 400128);
        int*    bs      = (int*)(ws + 600128);
        int2*   pack    = (int2*)(ws + 601152);
        __half* xh      = (__half*)(ws + 7001152);

        hipMemsetAsync(counts, 0, N_NODES * sizeof(int), stream);
        k_count_convert<<<N_EDGES / 256, 256, 0, stream>>>(
            dst, counts, (const float4*)x, (uint2*)xh);
        k_blocksum<<<NB, 256, 0, stream>>>(counts, bs);
        k_scanblocks<<<1, 256, 0, stream>>>(bs);
        k_offsets<<<NB, 256, 0, stream>>>(counts, bs, offsets, dinv);
        k_fill<<<(N_EDGES + 255) / 256, 256, 0, stream>>>(src, dst, dinv, counts, pack);
        k_agg<<<N_NODES / 4, 256, 0, stream>>>(x, xh, dinv, offsets, pack, W, b, out);
    } else if (ws_size >= NEED_B) {
        char* ws = (char*)d_ws;
        int*   counts     = (int*)(ws);
        int*   offsets    = (int*)(ws + 200000);
        float* dinv       = (float*)(ws + 400016);
        int*   bs         = (int*)(ws + 600016);
        int*   sorted_src = (int*)(ws + 601040);

        hipMemsetAsync(counts, 0, N_NODES * sizeof(int), stream);
        k_count_b<<<(N_EDGES + 255) / 256, 256, 0, stream>>>(dst, counts);
        k_blocksum<<<NB, 256, 0, stream>>>(counts, bs);
        k_scanblocks<<<1, 256, 0, stream>>>(bs);
        k_offsets<<<NB, 256, 0, stream>>>(counts, bs, offsets, dinv);
        k_fill_b<<<(N_EDGES + 255) / 256, 256, 0, stream>>>(src, dst, counts, sorted_src);
        k_agg_b<<<N_NODES / 4, 256, 0, stream>>>(x, dinv, offsets, sorted_src, W, b, out);
    } else {
        float* deg = (float*)d_ws;
        k_init_deg_f<<<(N_NODES + 255) / 256, 256, 0, stream>>>(deg);
        k_count_f<<<(N_EDGES + 255) / 256, 256, 0, stream>>>(dst, deg);
        k_dinv_f<<<(N_NODES + 255) / 256, 256, 0, stream>>>(deg);
        k_selfinit_f<<<(N_NODES * (F / 4) + 255) / 256, 256, 0, stream>>>(x, deg, out);
        k_scatter_f<<<(N_EDGES * 64 + 255) / 256, 256, 0, stream>>>(src, dst, x, deg, out);
        k_final_f<<<N_NODES / 4, 256, 0, stream>>>(W, b, out);
    }
}

// Round 5
// 129.921 us; speedup vs baseline: 2.6953x; 1.1453x over previous
//
#include <hip/hip_runtime.h>
#include <hip/hip_fp16.h>

#define N_NODES 50000
#define N_EDGES 800000
#define F 64
#define NB ((N_NODES + 255) / 256)   // 196 node-scan blocks
#define NBUCK 98                      // buckets of 512 nodes (dst >> 9)
#define BSHIFT 9
#define P1_BLOCKS ((N_EDGES + 1023) / 1024)   // 782

// ---------------------------------------------------------------------------
// GCNConv improved=True. Fully atomic-light pipeline:
//   1) bcount:   bucket histogram (LDS pre-agg, ~98 global atomics/block)
//   2) bscan:    exclusive scan of 98 bucket counts -> bbase, bcur
//   3) p1:       bin edges {src,dst} into staging, bucket-grouped (LDS ranks)
//   4) p2count:  per-bucket node-degree histogram in LDS -> counts (no globals)
//   5-7) node-level 3-phase scan -> offsets, dinv
//   8) p3:       in-bucket counting scatter via LDS cursors -> pack {src,norm}
//   9) convert:  xh = fp16(x)   (overlays dead staging buffer)
//  10) agg:      per-node wave: preload pack via shfl, independent row gathers,
//                fused @W + b, relu, log_softmax.
// Aggregate x BEFORE the weight transform ((A x) W == A (x W)).
// ---------------------------------------------------------------------------

union H2U { __half2 h; unsigned u; };

// ---- step 1: bucket histogram ----------------------------------------------
__global__ __launch_bounds__(1024) void k_bcount(const int* __restrict__ dst,
                                                 int* __restrict__ bcnt) {
    __shared__ int lcnt[NBUCK];
    int t = threadIdx.x;
    if (t < NBUCK) lcnt[t] = 0;
    __syncthreads();
    int e = blockIdx.x * 1024 + t;
    if (e < N_EDGES) atomicAdd(&lcnt[dst[e] >> BSHIFT], 1);
    __syncthreads();
    if (t < NBUCK && lcnt[t]) atomicAdd(&bcnt[t], lcnt[t]);
}

// ---- step 2: bucket scan ----------------------------------------------------
__global__ __launch_bounds__(128) void k_bscan(const int* __restrict__ bcnt,
                                               int* __restrict__ bbase,
                                               int* __restrict__ bcur) {
    __shared__ int sh[128];
    int t = threadIdx.x;
    int v = (t < NBUCK) ? bcnt[t] : 0;
    sh[t] = v;
    __syncthreads();
    for (int off = 1; off < 128; off <<= 1) {
        int u = (t >= off) ? sh[t - off] : 0;
        __syncthreads();
        sh[t] += u;
        __syncthreads();
    }
    int excl = sh[t] - v;
    if (t < NBUCK) { bbase[t] = excl; bcur[t] = excl; }
    if (t == 0) bbase[NBUCK] = N_EDGES;
}

// ---- step 3: bin edges into staging (bucket-grouped) ------------------------
__global__ __launch_bounds__(1024) void k_p1(const int* __restrict__ src,
                                             const int* __restrict__ dst,
                                             int* __restrict__ bcur,
                                             int2* __restrict__ staging) {
    __shared__ int lcnt[NBUCK];
    __shared__ int lbase[NBUCK];
    int t = threadIdx.x;
    if (t < NBUCK) lcnt[t] = 0;
    __syncthreads();
    int e = blockIdx.x * 1024 + t;
    int s = 0, d = 0, bk = 0, rank = 0;
    bool valid = (e < N_EDGES);
    if (valid) {
        s = src[e]; d = dst[e];
        bk = d >> BSHIFT;
        rank = atomicAdd(&lcnt[bk], 1);       // LDS
    }
    __syncthreads();
    if (t < NBUCK && lcnt[t]) lbase[t] = atomicAdd(&bcur[t], lcnt[t]);
    __syncthreads();
    if (valid) {
        int2 v; v.x = s; v.y = d;
        staging[lbase[bk] + rank] = v;        // ~80B grouped bursts
    }
}

// ---- step 4: per-bucket node-degree histogram -> counts ---------------------
__global__ __launch_bounds__(1024) void k_p2count(const int2* __restrict__ staging,
                                                  const int* __restrict__ bbase,
                                                  int* __restrict__ counts) {
    __shared__ int ncnt[512];
    int t = threadIdx.x;
    int b = blockIdx.x;
    int nb0 = b << BSHIFT;
    if (t < 512) ncnt[t] = 0;
    __syncthreads();
    int beg = bbase[b], end = bbase[b + 1];
    for (int i = beg + t; i < end; i += 1024)
        atomicAdd(&ncnt[staging[i].y - nb0], 1);   // LDS
    __syncthreads();
    if (t < 512) {
        int node = nb0 + t;
        if (node < N_NODES) counts[node] = ncnt[t];
    }
}

// ---- steps 5-7: node-level scan --------------------------------------------
__global__ __launch_bounds__(256) void k_blocksum(const int* __restrict__ counts,
                                                  int* __restrict__ bs) {
    __shared__ int sh[256];
    int t = threadIdx.x;
    int g = blockIdx.x * 256 + t;
    int v = (g < N_NODES) ? counts[g] : 0;
    sh[t] = v;
    __syncthreads();
    for (int off = 128; off > 0; off >>= 1) {
        if (t < off) sh[t] += sh[t + off];
        __syncthreads();
    }
    if (t == 0) bs[blockIdx.x] = sh[0];
}

__global__ __launch_bounds__(256) void k_scanblocks(int* __restrict__ bs) {
    __shared__ int sh[256];
    int t = threadIdx.x;
    int v = (t < NB) ? bs[t] : 0;
    sh[t] = v;
    __syncthreads();
    for (int off = 1; off < 256; off <<= 1) {
        int u = (t >= off) ? sh[t - off] : 0;
        __syncthreads();
        sh[t] += u;
        __syncthreads();
    }
    if (t < NB) bs[t] = sh[t] - v;
}

__global__ __launch_bounds__(256) void k_offsets(const int* __restrict__ counts,
                                                 const int* __restrict__ bs,
                                                 int* __restrict__ offsets,
                                                 float* __restrict__ dinv) {
    __shared__ int sh[256];
    int t = threadIdx.x;
    int g = blockIdx.x * 256 + t;
    int c = (g < N_NODES) ? counts[g] : 0;
    sh[t] = c;
    __syncthreads();
    for (int off = 1; off < 256; off <<= 1) {
        int u = (t >= off) ? sh[t - off] : 0;
        __syncthreads();
        sh[t] += u;
        __syncthreads();
    }
    int excl = sh[t] - c + bs[blockIdx.x];
    if (g < N_NODES) {
        offsets[g] = excl;
        dinv[g]    = rsqrtf((float)c + 2.0f);
    }
    if (g == 0) offsets[N_NODES] = N_EDGES;
}

// ---- step 8: in-bucket counting scatter via LDS cursors ---------------------
__global__ __launch_bounds__(1024) void k_p3(const int2* __restrict__ staging,
                                             const int* __restrict__ bbase,
                                             const int* __restrict__ offsets,
                                             const float* __restrict__ dinv,
                                             int2* __restrict__ pack) {
    __shared__ int lcur[512];
    int t = threadIdx.x;
    int b = blockIdx.x;
    int nb0 = b << BSHIFT;
    if (t < 512) {
        int node = nb0 + t;
        lcur[t] = (node < N_NODES) ? offsets[node] : 0;
    }
    __syncthreads();
    int beg = bbase[b], end = bbase[b + 1];
    for (int i = beg + t; i < end; i += 1024) {
        int2 sd = staging[i];
        int pos = atomicAdd(&lcur[sd.y - nb0], 1);    // LDS
        float nm = dinv[sd.x] * dinv[sd.y];
        int2 v; v.x = sd.x; v.y = __float_as_int(nm);
        pack[pos] = v;                                 // 65KB window per block
    }
}

// ---- step 9: x -> fp16 (overlays dead staging) ------------------------------
__global__ __launch_bounds__(256) void k_convert(const float4* __restrict__ x4,
                                                 uint2* __restrict__ xh8) {
    int t = blockIdx.x * 256 + threadIdx.x;   // grid exactly N*F/4 = 800000
    float4 v = x4[t];
    H2U a, b;
    a.h = __float22half2_rn(make_float2(v.x, v.y));
    b.h = __float22half2_rn(make_float2(v.z, v.w));
    uint2 o; o.x = a.u; o.y = b.u;
    xh8[t] = o;
}

// ---- step 10: aggregate + GEMM + relu + log_softmax -------------------------
// 8 nodes per 512-thread block; one wave per node.
// qe = lane>>3 (edge group), qc = lane&7 (16B chunk of the 128B fp16 row).
// pack entries preloaded (1/lane) and distributed via shfl -> row gathers are
// fully independent (no dependent pack load in the loop).
__global__ __launch_bounds__(512) void k_agg(const float* __restrict__ x,
                                             const __half* __restrict__ xh,
                                             const float* __restrict__ dinv,
                                             const int* __restrict__ offsets,
                                             const int2* __restrict__ pack,
                                             const float* __restrict__ W,
                                             const float* __restrict__ b,
                                             float* __restrict__ out) {
    __shared__ float sW[F * F];
    __shared__ float srow[8][F];
    int t = threadIdx.x;
    {
        const float4* W4 = reinterpret_cast<const float4*>(W);
        float4* sW4 = reinterpret_cast<float4*>(sW);
        for (int i = t; i < F * F / 4; i += 512) sW4[i] = W4[i];
    }

    int wid = t >> 6, lane = t & 63;
    int n = blockIdx.x * 8 + wid;            // 6250 * 8 == 50000 exactly
    int qe = lane >> 3, qc = lane & 7;
    float dn = dinv[n];

    int beg = offsets[n], end = offsets[n + 1];
    int deg = end - beg;

    // preload up to 64 pack entries, one per lane; empty slots = {0,0} (nm=0)
    int2 pl = make_int2(0, 0);
    if (lane < deg) pl = pack[beg + lane];

    float acc[8];
#pragma unroll
    for (int i = 0; i < 8; ++i) acc[i] = 0.f;

    const uint4* xh16 = reinterpret_cast<const uint4*>(xh);
    int lim = min(deg, 64);

    for (int r = 0; r < lim; r += 16) {      // 16 edges/iter, 2 indep row loads
        int e0 = r + qe, e1 = r + 8 + qe;
        int   s0  = __shfl(pl.x, e0);
        float nm0 = __int_as_float(__shfl(pl.y, e0));
        int   s1  = __shfl(pl.x, e1);
        float nm1 = __int_as_float(__shfl(pl.y, e1));
        uint4 r0 = xh16[(size_t)s0 * (F / 8) + qc];
        uint4 r1 = xh16[(size_t)s1 * (F / 8) + qc];
        H2U u0, u1, u2, u3;
        float2 f;
        u0.u = r0.x; u1.u = r0.y; u2.u = r0.z; u3.u = r0.w;
        f = __half22float2(u0.h); acc[0] = fmaf(nm0, f.x, acc[0]); acc[1] = fmaf(nm0, f.y, acc[1]);
        f = __half22float2(u1.h); acc[2] = fmaf(nm0, f.x, acc[2]); acc[3] = fmaf(nm0, f.y, acc[3]);
        f = __half22float2(u2.h); acc[4] = fmaf(nm0, f.x, acc[4]); acc[5] = fmaf(nm0, f.y, acc[5]);
        f = __half22float2(u3.h); acc[6] = fmaf(nm0, f.x, acc[6]); acc[7] = fmaf(nm0, f.y, acc[7]);
        u0.u = r1.x; u1.u = r1.y; u2.u = r1.z; u3.u = r1.w;
        f = __half22float2(u0.h); acc[0] = fmaf(nm1, f.x, acc[0]); acc[1] = fmaf(nm1, f.y, acc[1]);
        f = __half22float2(u1.h); acc[2] = fmaf(nm1, f.x, acc[2]); acc[3] = fmaf(nm1, f.y, acc[3]);
        f = __half22float2(u2.h); acc[4] = fmaf(nm1, f.x, acc[4]); acc[5] = fmaf(nm1, f.y, acc[5]);
        f = __half22float2(u3.h); acc[6] = fmaf(nm1, f.x, acc[6]); acc[7] = fmaf(nm1, f.y, acc[7]);
    }
    // ultra-rare overflow (deg > 64)
    for (int base = beg + 64; base < end; base += 8) {
        int e = base + qe;
        int ec = min(e, end - 1);
        int2 p = pack[ec];
        float nm = (e < end) ? __int_as_float(p.y) : 0.f;
        uint4 r = xh16[(size_t)p.x * (F / 8) + qc];
        H2U u0, u1, u2, u3;
        float2 f;
        u0.u = r.x; u1.u = r.y; u2.u = r.z; u3.u = r.w;
        f = __half22float2(u0.h); acc[0] = fmaf(nm, f.x, acc[0]); acc[1] = fmaf(nm, f.y, acc[1]);
        f = __half22float2(u1.h); acc[2] = fmaf(nm, f.x, acc[2]); acc[3] = fmaf(nm, f.y, acc[3]);
        f = __half22float2(u2.h); acc[4] = fmaf(nm, f.x, acc[4]); acc[5] = fmaf(nm, f.y, acc[5]);
        f = __half22float2(u3.h); acc[6] = fmaf(nm, f.x, acc[6]); acc[7] = fmaf(nm, f.y, acc[7]);
    }

    // reduce across the 8 edge groups (lane bits 3,4,5)
#pragma unroll
    for (int i = 0; i < 8; ++i) {
        acc[i] += __shfl_xor(acc[i], 8);
        acc[i] += __shfl_xor(acc[i], 16);
        acc[i] += __shfl_xor(acc[i], 32);
    }

    // self loop (weight 2), f32 x
    float c2 = 2.0f * dn * dn;
    const float4* xn = reinterpret_cast<const float4*>(x + (size_t)n * F);
    float4 s0 = xn[qc * 2], s1 = xn[qc * 2 + 1];
    acc[0] = fmaf(c2, s0.x, acc[0]); acc[1] = fmaf(c2, s0.y, acc[1]);
    acc[2] = fmaf(c2, s0.z, acc[2]); acc[3] = fmaf(c2, s0.w, acc[3]);
    acc[4] = fmaf(c2, s1.x, acc[4]); acc[5] = fmaf(c2, s1.y, acc[5]);
    acc[6] = fmaf(c2, s1.z, acc[6]); acc[7] = fmaf(c2, s1.w, acc[7]);

    if (qe == 0) {
        float4* dstp = reinterpret_cast<float4*>(&srow[wid][qc * 8]);
        float4 w0, w1;
        w0.x = acc[0]; w0.y = acc[1]; w0.z = acc[2]; w0.w = acc[3];
        w1.x = acc[4]; w1.y = acc[5]; w1.z = acc[6]; w1.w = acc[7];
        dstp[0] = w0; dstp[1] = w1;
    }
    __syncthreads();                          // also covers sW staging

    float y = b[lane];
#pragma unroll
    for (int k = 0; k < F; ++k)
        y = fmaf(srow[wid][k], sW[k * F + lane], y);
    y = fmaxf(y, 0.0f);

    float mx = y;
#pragma unroll
    for (int off = 32; off > 0; off >>= 1)
        mx = fmaxf(mx, __shfl_xor(mx, off));
    float ex = __expf(y - mx);
    float ss = ex;
#pragma unroll
    for (int off = 32; off > 0; off >>= 1)
        ss += __shfl_xor(ss, off);

    out[n * F + lane] = y - mx - __logf(ss);
}

// ---------------- tier-B fallback (round-3 f32 path) ------------------------

__global__ void k_count_b(const int* __restrict__ dst, int* __restrict__ counts) {
    int e = blockIdx.x * blockDim.x + threadIdx.x;
    if (e < N_EDGES) atomicAdd(&counts[dst[e]], 1);
}
__global__ __launch_bounds__(256) void k_offsets_b(int* __restrict__ counts,
                                                   const int* __restrict__ bs,
                                                   int* __restrict__ offsets,
                                                   float* __restrict__ dinv) {
    __shared__ int sh[256];
    int t = threadIdx.x;
    int g = blockIdx.x * 256 + t;
    int c = (g < N_NODES) ? counts[g] : 0;
    sh[t] = c;
    __syncthreads();
    for (int off = 1; off < 256; off <<= 1) {
        int u = (t >= off) ? sh[t - off] : 0;
        __syncthreads();
        sh[t] += u;
        __syncthreads();
    }
    int excl = sh[t] - c + bs[blockIdx.x];
    if (g < N_NODES) {
        offsets[g] = excl;
        counts[g]  = excl;
        dinv[g]    = rsqrtf((float)c + 2.0f);
    }
    if (g == 0) offsets[N_NODES] = N_EDGES;
}
__global__ void k_fill_b(const int* __restrict__ src, const int* __restrict__ dst,
                         int* __restrict__ cursor, int* __restrict__ sorted_src) {
    int e = blockIdx.x * blockDim.x + threadIdx.x;
    if (e < N_EDGES) {
        int pos = atomicAdd(&cursor[dst[e]], 1);
        sorted_src[pos] = src[e];
    }
}
__global__ __launch_bounds__(256) void k_agg_b(const float* __restrict__ x,
                                               const float* __restrict__ dinv,
                                               const int* __restrict__ offsets,
                                               const int* __restrict__ sorted_src,
                                               const float* __restrict__ W,
                                               const float* __restrict__ b,
                                               float* __restrict__ out) {
    __shared__ float sW[F * F];
    __shared__ float srow[4][F];
    int t = threadIdx.x;
    for (int i = t; i < F * F; i += 256) sW[i] = W[i];
    int wid = t >> 6, lane = t & 63;
    int n = blockIdx.x * 4 + wid;
    int qe = lane >> 4, qc = lane & 15;
    float dn = dinv[n];
    int beg = offsets[n], end = offsets[n + 1];
    float4 acc = make_float4(0.f, 0.f, 0.f, 0.f);
    for (int base = beg; base < end; base += 4) {
        int e = base + qe;
        int s = n; float nm = 0.f;
        if (e < end) { s = sorted_src[e]; nm = dn * dinv[s]; }
        float4 v = reinterpret_cast<const float4*>(x + (size_t)s * F)[qc];
        acc.x = fmaf(nm, v.x, acc.x); acc.y = fmaf(nm, v.y, acc.y);
        acc.z = fmaf(nm, v.z, acc.z); acc.w = fmaf(nm, v.w, acc.w);
    }
    acc.x += __shfl_xor(acc.x, 16); acc.y += __shfl_xor(acc.y, 16);
    acc.z += __shfl_xor(acc.z, 16); acc.w += __shfl_xor(acc.w, 16);
    acc.x += __shfl_xor(acc.x, 32); acc.y += __shfl_xor(acc.y, 32);
    acc.z += __shfl_xor(acc.z, 32); acc.w += __shfl_xor(acc.w, 32);
    float c2 = 2.0f * dn * dn;
    float4 xv = reinterpret_cast<const float4*>(x + (size_t)n * F)[qc];
    acc.x = fmaf(c2, xv.x, acc.x); acc.y = fmaf(c2, xv.y, acc.y);
    acc.z = fmaf(c2, xv.z, acc.z); acc.w = fmaf(c2, xv.w, acc.w);
    if (qe == 0) reinterpret_cast<float4*>(&srow[wid][0])[qc] = acc;
    __syncthreads();
    float y = b[lane];
#pragma unroll
    for (int k = 0; k < F; ++k) y = fmaf(srow[wid][k], sW[k * F + lane], y);
    y = fmaxf(y, 0.0f);
    float m = y;
#pragma unroll
    for (int off = 32; off > 0; off >>= 1) m = fmaxf(m, __shfl_xor(m, off));
    float ex = __expf(y - m);
    float ss = ex;
#pragma unroll
    for (int off = 32; off > 0; off >>= 1) ss += __shfl_xor(ss, off);
    out[n * F + lane] = y - m - __logf(ss);
}

// ---------------- tier-C fallback (atomic scatter) --------------------------

__global__ void k_init_deg_f(float* __restrict__ deg) {
    int i = blockIdx.x * blockDim.x + threadIdx.x;
    if (i < N_NODES) deg[i] = 2.0f;
}
__global__ void k_count_f(const int* __restrict__ dst, float* __restrict__ deg) {
    int e = blockIdx.x * blockDim.x + threadIdx.x;
    if (e < N_EDGES) atomicAdd(&deg[dst[e]], 1.0f);
}
__global__ void k_dinv_f(float* __restrict__ deg) {
    int i = blockIdx.x * blockDim.x + threadIdx.x;
    if (i < N_NODES) deg[i] = rsqrtf(deg[i]);
}
__global__ void k_selfinit_f(const float* __restrict__ x, const float* __restrict__ dinv,
                             float* __restrict__ agg) {
    int t = blockIdx.x * blockDim.x + threadIdx.x;
    if (t >= N_NODES * (F / 4)) return;
    int n = t >> 4;
    float d = dinv[n];
    float c = 2.0f * d * d;
    float4 v = reinterpret_cast<const float4*>(x)[t];
    float4 o; o.x = c*v.x; o.y = c*v.y; o.z = c*v.z; o.w = c*v.w;
    reinterpret_cast<float4*>(agg)[t] = o;
}
__global__ __launch_bounds__(256) void k_scatter_f(const int* __restrict__ src,
                                                   const int* __restrict__ dst,
                                                   const float* __restrict__ x,
                                                   const float* __restrict__ dinv,
                                                   float* __restrict__ agg) {
    int wave = (blockIdx.x * blockDim.x + threadIdx.x) >> 6;
    int lane = threadIdx.x & 63;
    if (wave >= N_EDGES) return;
    int s = src[wave], d = dst[wave];
    atomicAdd(&agg[d * F + lane], dinv[s] * dinv[d] * x[s * F + lane]);
}
__global__ __launch_bounds__(256) void k_final_f(const float* __restrict__ W,
                                                 const float* __restrict__ b,
                                                 float* __restrict__ out) {
    __shared__ float sW[F * F];
    __shared__ float srow[4][F];
    int t = threadIdx.x;
    for (int i = t; i < F * F; i += 256) sW[i] = W[i];
    int wid = t >> 6, lane = t & 63;
    int n = blockIdx.x * 4 + wid;
    float rv = out[n * F + lane];
    srow[wid][lane] = rv;
    __syncthreads();
    float y = b[lane];
#pragma unroll
    for (int k = 0; k < F; ++k) y = fmaf(srow[wid][k], sW[k * F + lane], y);
    y = fmaxf(y, 0.0f);
    float m = y;
#pragma unroll
    for (int off = 32; off > 0; off >>= 1) m = fmaxf(m, __shfl_xor(m, off));
    float ex = __expf(y - m);
    float ss = ex;
#pragma unroll
    for (int off = 32; off > 0; off >>= 1) ss += __shfl_xor(ss, off);
    out[n * F + lane] = y - m - __logf(ss);
}

// ---------------------------------------------------------------------------

extern "C" void kernel_launch(void* const* d_in, const int* in_sizes, int n_in,
                              void* d_out, int out_size, void* d_ws, size_t ws_size,
                              hipStream_t stream) {
    const float* x    = (const float*)d_in[0];
    const int*   eidx = (const int*)d_in[1];   // [2][E]: row0 = src, row1 = dst
    const float* W    = (const float*)d_in[2];
    const float* b    = (const float*)d_in[3];
    const int* src = eidx;
    const int* dst = eidx + N_EDGES;
    float* out = (float*)d_out;

    // Tier-A2 ws layout (byte offsets):
    //   counts        [0,       204800)
    //   offsets       [204800,  409600)   (50001 ints)
    //   dinv          [409600,  614400)
    //   bcnt          [614400,  615424)
    //   bbase         [615424,  616448)   (99 ints)
    //   bcur          [616448,  617472)
    //   pack (int2)   [617472,  7017472)
    //   staging/xh    [7017472, 13417472) (int2 / half, time-disjoint)
    const size_t NEED_A2 = 13417472;
    const size_t NEED_B  = 3801040;

    if (ws_size >= NEED_A2) {
        char* ws = (char*)d_ws;
        int*    counts  = (int*)(ws);
        int*    offsets = (int*)(ws + 204800);
        float*  dinv    = (float*)(ws + 409600);
        int*    bcnt    = (int*)(ws + 614400);
        int*    bbase   = (int*)(ws + 615424);
        int*    bcur    = (int*)(ws + 616448);
        int2*   pack    = (int2*)(ws + 617472);
        int2*   staging = (int2*)(ws + 7017472);
        __half* xh      = (__half*)(ws + 7017472);

        hipMemsetAsync(bcnt, 0, NBUCK * sizeof(int), stream);
        k_bcount<<<P1_BLOCKS, 1024, 0, stream>>>(dst, bcnt);
        k_bscan<<<1, 128, 0, stream>>>(bcnt, bbase, bcur);
        k_p1<<<P1_BLOCKS, 1024, 0, stream>>>(src, dst, bcur, staging);
        k_p2count<<<NBUCK, 1024, 0, stream>>>(staging, bbase, counts);
        k_blocksum<<<NB, 256, 0, stream>>>(counts, bcnt /*unused*/ == bcnt ? (int*)(ws + 614400) : nullptr);
        // NOTE: bs reuses the bcnt slab (dead after bscan); 196 ints < 1024B? No:
        // 196*4 = 784 bytes < 1024 ✓
        k_scanblocks<<<1, 256, 0, stream>>>((int*)(ws + 614400));
        k_offsets<<<NB, 256, 0, stream>>>(counts, (int*)(ws + 614400), offsets, dinv);
        k_p3<<<NBUCK, 1024, 0, stream>>>(staging, bbase, offsets, dinv, pack);
        k_convert<<<N_NODES * (F / 4) / 256, 256, 0, stream>>>((const float4*)x, (uint2*)xh);
        k_agg<<<N_NODES / 8, 512, 0, stream>>>(x, xh, dinv, offsets, pack, W, b, out);
    } else if (ws_size >= NEED_B) {
        char* ws = (char*)d_ws;
        int*   counts     = (int*)(ws);
        int*   offsets    = (int*)(ws + 200000);
        float* dinv       = (float*)(ws + 400016);
        int*   bs         = (int*)(ws + 600016);
        int*   sorted_src = (int*)(ws + 601040);

        hipMemsetAsync(counts, 0, N_NODES * sizeof(int), stream);
        k_count_b<<<(N_EDGES + 255) / 256, 256, 0, stream>>>(dst, counts);
        k_blocksum<<<NB, 256, 0, stream>>>(counts, bs);
        k_scanblocks<<<1, 256, 0, stream>>>(bs);
        k_offsets_b<<<NB, 256, 0, stream>>>(counts, bs, offsets, dinv);
        k_fill_b<<<(N_EDGES + 255) / 256, 256, 0, stream>>>(src, dst, counts, sorted_src);
        k_agg_b<<<N_NODES / 4, 256, 0, stream>>>(x, dinv, offsets, sorted_src, W, b, out);
    } else {
        float* deg = (float*)d_ws;
        k_init_deg_f<<<(N_NODES + 255) / 256, 256, 0, stream>>>(deg);
        k_count_f<<<(N_EDGES + 255) / 256, 256, 0, stream>>>(dst, deg);
        k_dinv_f<<<(N_NODES + 255) / 256, 256, 0, stream>>>(deg);
        k_selfinit_f<<<(N_NODES * (F / 4) + 255) / 256, 256, 0, stream>>>(x, deg, out);
        k_scatter_f<<<(N_EDGES * 64 + 255) / 256, 256, 0, stream>>>(src, dst, x, deg, out);
        k_final_f<<<N_NODES / 4, 256, 0, stream>>>(W, b, out);
    }
}

// Round 6
// 110.595 us; speedup vs baseline: 3.1663x; 1.1748x over previous
//
#include <hip/hip_runtime.h>
#include <hip/hip_fp16.h>

#define N_NODES 50000
#define N_EDGES 800000
#define F 64
#define NB ((N_NODES + 255) / 256)   // tier-B node-scan blocks
#define NBUCK 98                      // buckets of 512 nodes (dst >> 9)
#define BSHIFT 9
#define P1_BLOCKS ((N_EDGES + 1023) / 1024)   // 782
#define NPB 32                        // nodes per k_agg block (8 waves x 4)

// ---------------------------------------------------------------------------
// GCNConv improved=True. Pipeline (7 dispatches):
//   1) memset bcnt
//   2) bcount: bucket histogram (LDS pre-agg)
//   3) bscan:  scan of 98 bucket counts -> bbase, bcur; offsets[N]=E
//   4) p1:     bin edges {src,dst} into staging, bucket-grouped (LDS ranks)
//   5) p23:    per-bucket: node histogram + in-LDS 512-scan -> offsets,dinv;
//              then in-bucket counting scatter via LDS cursors -> pack (src)
//   6) convert: xh = fp16(x)  (overlays dead staging)
//   7) agg:    8 waves x 4 nodes: preload pack+norm, shfl-distributed
//              independent fp16 row gathers, 4-node-interleaved GEMM from LDS
//              (sW read shared across 4 rows), relu, log_softmax.
// Aggregate x BEFORE the weight transform ((A x) W == A (x W)).
// ---------------------------------------------------------------------------

union H2U { __half2 h; unsigned u; };

// ---- step 2: bucket histogram ----------------------------------------------
__global__ __launch_bounds__(1024) void k_bcount(const int* __restrict__ dst,
                                                 int* __restrict__ bcnt) {
    __shared__ int lcnt[NBUCK];
    int t = threadIdx.x;
    if (t < NBUCK) lcnt[t] = 0;
    __syncthreads();
    int e = blockIdx.x * 1024 + t;
    if (e < N_EDGES) atomicAdd(&lcnt[dst[e] >> BSHIFT], 1);
    __syncthreads();
    if (t < NBUCK && lcnt[t]) atomicAdd(&bcnt[t], lcnt[t]);
}

// ---- step 3: bucket scan ----------------------------------------------------
__global__ __launch_bounds__(128) void k_bscan(const int* __restrict__ bcnt,
                                               int* __restrict__ bbase,
                                               int* __restrict__ bcur,
                                               int* __restrict__ offsets) {
    __shared__ int sh[128];
    int t = threadIdx.x;
    int v = (t < NBUCK) ? bcnt[t] : 0;
    sh[t] = v;
    __syncthreads();
    for (int off = 1; off < 128; off <<= 1) {
        int u = (t >= off) ? sh[t - off] : 0;
        __syncthreads();
        sh[t] += u;
        __syncthreads();
    }
    int excl = sh[t] - v;
    if (t < NBUCK) { bbase[t] = excl; bcur[t] = excl; }
    if (t == 0) { bbase[NBUCK] = N_EDGES; offsets[N_NODES] = N_EDGES; }
}

// ---- step 4: bin edges into staging (bucket-grouped) ------------------------
__global__ __launch_bounds__(1024) void k_p1(const int* __restrict__ src,
                                             const int* __restrict__ dst,
                                             int* __restrict__ bcur,
                                             int2* __restrict__ staging) {
    __shared__ int lcnt[NBUCK];
    __shared__ int lbase[NBUCK];
    int t = threadIdx.x;
    if (t < NBUCK) lcnt[t] = 0;
    __syncthreads();
    int e = blockIdx.x * 1024 + t;
    int s = 0, d = 0, bk = 0, rank = 0;
    bool valid = (e < N_EDGES);
    if (valid) {
        s = src[e]; d = dst[e];
        bk = d >> BSHIFT;
        rank = atomicAdd(&lcnt[bk], 1);       // LDS
    }
    __syncthreads();
    if (t < NBUCK && lcnt[t]) lbase[t] = atomicAdd(&bcur[t], lcnt[t]);
    __syncthreads();
    if (valid) {
        int2 v; v.x = s; v.y = d;
        staging[lbase[bk] + rank] = v;        // grouped bursts
    }
}

// ---- step 5: per-bucket histogram + LDS scan -> offsets/dinv, then scatter --
__global__ __launch_bounds__(1024) void k_p23(const int2* __restrict__ staging,
                                              const int* __restrict__ bbase,
                                              int* __restrict__ offsets,
                                              float* __restrict__ dinv,
                                              int* __restrict__ pack) {
    __shared__ int ncnt[512];
    __shared__ int lcur[512];
    int t = threadIdx.x;
    int b = blockIdx.x;
    int nb0 = b << BSHIFT;
    if (t < 512) ncnt[t] = 0;
    __syncthreads();
    int beg = bbase[b], end = bbase[b + 1];
    for (int i = beg + t; i < end; i += 1024)
        atomicAdd(&ncnt[staging[i].y - nb0], 1);   // LDS
    __syncthreads();
    int c = (t < 512) ? ncnt[t] : 0;
    // inclusive Hillis-Steele scan of ncnt[0..511]
    for (int off = 1; off < 512; off <<= 1) {
        int u = (t < 512 && t >= off) ? ncnt[t - off] : 0;
        __syncthreads();
        if (t < 512) ncnt[t] += u;
        __syncthreads();
    }
    if (t < 512) {
        int excl = ncnt[t] - c;
        int goff = beg + excl;
        lcur[t] = goff;
        int node = nb0 + t;
        if (node < N_NODES) {
            offsets[node] = goff;
            dinv[node] = rsqrtf((float)c + 2.0f);
        }
    }
    __syncthreads();
    for (int i = beg + t; i < end; i += 1024) {
        int2 sd = staging[i];                      // L2-hot re-read
        int pos = atomicAdd(&lcur[sd.y - nb0], 1); // LDS cursor
        pack[pos] = sd.x;                          // 4B store, 32KB window
    }
}

// ---- step 6: x -> fp16 (overlays dead staging) ------------------------------
__global__ __launch_bounds__(256) void k_convert(const float4* __restrict__ x4,
                                                 uint2* __restrict__ xh8) {
    int t = blockIdx.x * 256 + threadIdx.x;   // grid exactly N*F/4 = 800000
    float4 v = x4[t];
    H2U a, b;
    a.h = __float22half2_rn(make_float2(v.x, v.y));
    b.h = __float22half2_rn(make_float2(v.z, v.w));
    uint2 o; o.x = a.u; o.y = b.u;
    xh8[t] = o;
}

// ---- step 7: aggregate + GEMM + relu + log_softmax --------------------------
// 512 threads = 8 waves; wave handles 4 nodes. Edge phase: qe=lane>>4 picks
// 1 of 4 parallel edges, qc=lane&15 picks the 8B (4-half) slice of the 128B
// fp16 row; acc[4] = features qc*4..qc*4+3; reduce = 2 shfl_xor per acc.
// GEMM: wave-private srows; sW[k][lane] read once, used for 4 rows.
__global__ __launch_bounds__(512) void k_agg(const float* __restrict__ x,
                                             const __half* __restrict__ xh,
                                             const float* __restrict__ dinv,
                                             const int* __restrict__ offsets,
                                             const int* __restrict__ pack,
                                             const float* __restrict__ W,
                                             const float* __restrict__ bias,
                                             float* __restrict__ out) {
    __shared__ float sW[F * F];
    __shared__ float srow[NPB][F];
    int t = threadIdx.x;
    {
        const float4* W4 = reinterpret_cast<const float4*>(W);
        float4* s4 = reinterpret_cast<float4*>(sW);
        for (int i = t; i < F * F / 4; i += 512) s4[i] = W4[i];
    }
    __syncthreads();

    int wid = t >> 6, lane = t & 63;
    int qe = lane >> 4, qc = lane & 15;
    int nbase = blockIdx.x * NPB + wid * 4;
    const uint2* xh8 = reinterpret_cast<const uint2*>(xh);

    // ---- preload phase: offsets, dinv, pack entry + norm per lane ----
    int  begs[4], degs[4], pls[4];
    float dns[4], nms[4];
#pragma unroll
    for (int i = 0; i < 4; ++i) {
        int n = nbase + i;
        if (n < N_NODES) {
            int o0 = offsets[n], o1 = offsets[n + 1];
            begs[i] = o0; degs[i] = o1 - o0; dns[i] = dinv[n];
        } else { begs[i] = 0; degs[i] = 0; dns[i] = 0.f; }
    }
#pragma unroll
    for (int i = 0; i < 4; ++i) {
        int s = 0; float nm = 0.f;
        if (lane < degs[i]) {
            s = pack[begs[i] + lane];
            nm = dns[i] * dinv[s];
        }
        pls[i] = s; nms[i] = nm;
    }

    // ---- per-node aggregation ----
#pragma unroll
    for (int i = 0; i < 4; ++i) {
        int n = nbase + i;
        float a0 = 0.f, a1 = 0.f, a2 = 0.f, a3 = 0.f;
        int deg = degs[i];
        int lim = min(deg, 64);
        for (int r = 0; r < lim; r += 8) {        // 8 edges/iter, 2 indep loads
            int e0 = r + qe, e1 = r + 4 + qe;     // always <= 63
            int   s0 = __shfl(pls[i], e0);
            float m0 = __shfl(nms[i], e0);
            int   s1 = __shfl(pls[i], e1);
            float m1 = __shfl(nms[i], e1);
            uint2 r0 = xh8[(size_t)s0 * 16 + qc];
            uint2 r1 = xh8[(size_t)s1 * 16 + qc];
            H2U u0, u1; float2 f;
            u0.u = r0.x; u1.u = r0.y;
            f = __half22float2(u0.h); a0 = fmaf(m0, f.x, a0); a1 = fmaf(m0, f.y, a1);
            f = __half22float2(u1.h); a2 = fmaf(m0, f.x, a2); a3 = fmaf(m0, f.y, a3);
            u0.u = r1.x; u1.u = r1.y;
            f = __half22float2(u0.h); a0 = fmaf(m1, f.x, a0); a1 = fmaf(m1, f.y, a1);
            f = __half22float2(u1.h); a2 = fmaf(m1, f.x, a2); a3 = fmaf(m1, f.y, a3);
        }
        // ultra-rare overflow (deg > 64)
        int dend = begs[i] + deg;
        for (int base = begs[i] + 64; base < dend; base += 8) {
            int e0 = base + qe, e1 = base + 4 + qe;
            int s0 = 0, s1 = 0; float m0 = 0.f, m1 = 0.f;
            if (e0 < dend) { s0 = pack[e0]; m0 = dns[i] * dinv[s0]; }
            if (e1 < dend) { s1 = pack[e1]; m1 = dns[i] * dinv[s1]; }
            uint2 r0 = xh8[(size_t)s0 * 16 + qc];
            uint2 r1 = xh8[(size_t)s1 * 16 + qc];
            H2U u0, u1; float2 f;
            u0.u = r0.x; u1.u = r0.y;
            f = __half22float2(u0.h); a0 = fmaf(m0, f.x, a0); a1 = fmaf(m0, f.y, a1);
            f = __half22float2(u1.h); a2 = fmaf(m0, f.x, a2); a3 = fmaf(m0, f.y, a3);
            u0.u = r1.x; u1.u = r1.y;
            f = __half22float2(u0.h); a0 = fmaf(m1, f.x, a0); a1 = fmaf(m1, f.y, a1);
            f = __half22float2(u1.h); a2 = fmaf(m1, f.x, a2); a3 = fmaf(m1, f.y, a3);
        }
        // reduce across the 4 edge groups (lane bits 4,5)
        a0 += __shfl_xor(a0, 16); a0 += __shfl_xor(a0, 32);
        a1 += __shfl_xor(a1, 16); a1 += __shfl_xor(a1, 32);
        a2 += __shfl_xor(a2, 16); a2 += __shfl_xor(a2, 32);
        a3 += __shfl_xor(a3, 16); a3 += __shfl_xor(a3, 32);
        // self loop (weight 2), f32 x; write wave-private srow
        if (qe == 0 && n < N_NODES) {
            float c2 = 2.0f * dns[i] * dns[i];
            float4 xv = reinterpret_cast<const float4*>(x + (size_t)n * F)[qc];
            a0 = fmaf(c2, xv.x, a0); a1 = fmaf(c2, xv.y, a1);
            a2 = fmaf(c2, xv.z, a2); a3 = fmaf(c2, xv.w, a3);
            float4 w; w.x = a0; w.y = a1; w.z = a2; w.w = a3;
            *reinterpret_cast<float4*>(&srow[wid * 4 + i][qc * 4]) = w;
        }
    }

    // wave-private srows: no barrier needed, just drain LDS writes
    asm volatile("s_waitcnt lgkmcnt(0)" ::: "memory");

    // ---- 4-node-interleaved GEMM: y[c] = sum_k srow[k] * W[k][c] ----
    float bl = bias[lane];
    float y0 = bl, y1 = bl, y2 = bl, y3 = bl;
#pragma unroll 4
    for (int j = 0; j < 16; ++j) {
        float4 r0 = *reinterpret_cast<const float4*>(&srow[wid * 4 + 0][j * 4]);
        float4 r1 = *reinterpret_cast<const float4*>(&srow[wid * 4 + 1][j * 4]);
        float4 r2 = *reinterpret_cast<const float4*>(&srow[wid * 4 + 2][j * 4]);
        float4 r3 = *reinterpret_cast<const float4*>(&srow[wid * 4 + 3][j * 4]);
        float w0 = sW[(4 * j + 0) * F + lane];
        float w1 = sW[(4 * j + 1) * F + lane];
        float w2 = sW[(4 * j + 2) * F + lane];
        float w3 = sW[(4 * j + 3) * F + lane];
        y0 = fmaf(r0.x, w0, y0); y0 = fmaf(r0.y, w1, y0); y0 = fmaf(r0.z, w2, y0); y0 = fmaf(r0.w, w3, y0);
        y1 = fmaf(r1.x, w0, y1); y1 = fmaf(r1.y, w1, y1); y1 = fmaf(r1.z, w2, y1); y1 = fmaf(r1.w, w3, y1);
        y2 = fmaf(r2.x, w0, y2); y2 = fmaf(r2.y, w1, y2); y2 = fmaf(r2.z, w2, y2); y2 = fmaf(r2.w, w3, y2);
        y3 = fmaf(r3.x, w0, y3); y3 = fmaf(r3.y, w1, y3); y3 = fmaf(r3.z, w2, y3); y3 = fmaf(r3.w, w3, y3);
    }

    float ys[4] = { y0, y1, y2, y3 };
#pragma unroll
    for (int i = 0; i < 4; ++i) {
        float y = fmaxf(ys[i], 0.0f);             // relu
        float mx = y;
#pragma unroll
        for (int off = 32; off > 0; off >>= 1)
            mx = fmaxf(mx, __shfl_xor(mx, off));
        float ex = __expf(y - mx);
        float ss = ex;
#pragma unroll
        for (int off = 32; off > 0; off >>= 1)
            ss += __shfl_xor(ss, off);
        int n = nbase + i;
        if (n < N_NODES) out[n * F + lane] = y - mx - __logf(ss);
    }
}

// ---------------- tier-B fallback (round-3 f32 path) ------------------------

__global__ void k_count_b(const int* __restrict__ dst, int* __restrict__ counts) {
    int e = blockIdx.x * blockDim.x + threadIdx.x;
    if (e < N_EDGES) atomicAdd(&counts[dst[e]], 1);
}
__global__ __launch_bounds__(256) void k_blocksum(const int* __restrict__ counts,
                                                  int* __restrict__ bs) {
    __shared__ int sh[256];
    int t = threadIdx.x;
    int g = blockIdx.x * 256 + t;
    int v = (g < N_NODES) ? counts[g] : 0;
    sh[t] = v;
    __syncthreads();
    for (int off = 128; off > 0; off >>= 1) {
        if (t < off) sh[t] += sh[t + off];
        __syncthreads();
    }
    if (t == 0) bs[blockIdx.x] = sh[0];
}
__global__ __launch_bounds__(256) void k_scanblocks(int* __restrict__ bs) {
    __shared__ int sh[256];
    int t = threadIdx.x;
    int v = (t < NB) ? bs[t] : 0;
    sh[t] = v;
    __syncthreads();
    for (int off = 1; off < 256; off <<= 1) {
        int u = (t >= off) ? sh[t - off] : 0;
        __syncthreads();
        sh[t] += u;
        __syncthreads();
    }
    if (t < NB) bs[t] = sh[t] - v;
}
__global__ __launch_bounds__(256) void k_offsets_b(int* __restrict__ counts,
                                                   const int* __restrict__ bs,
                                                   int* __restrict__ offsets,
                                                   float* __restrict__ dinv) {
    __shared__ int sh[256];
    int t = threadIdx.x;
    int g = blockIdx.x * 256 + t;
    int c = (g < N_NODES) ? counts[g] : 0;
    sh[t] = c;
    __syncthreads();
    for (int off = 1; off < 256; off <<= 1) {
        int u = (t >= off) ? sh[t - off] : 0;
        __syncthreads();
        sh[t] += u;
        __syncthreads();
    }
    int excl = sh[t] - c + bs[blockIdx.x];
    if (g < N_NODES) {
        offsets[g] = excl;
        counts[g]  = excl;
        dinv[g]    = rsqrtf((float)c + 2.0f);
    }
    if (g == 0) offsets[N_NODES] = N_EDGES;
}
__global__ void k_fill_b(const int* __restrict__ src, const int* __restrict__ dst,
                         int* __restrict__ cursor, int* __restrict__ sorted_src) {
    int e = blockIdx.x * blockDim.x + threadIdx.x;
    if (e < N_EDGES) {
        int pos = atomicAdd(&cursor[dst[e]], 1);
        sorted_src[pos] = src[e];
    }
}
__global__ __launch_bounds__(256) void k_agg_b(const float* __restrict__ x,
                                               const float* __restrict__ dinv,
                                               const int* __restrict__ offsets,
                                               const int* __restrict__ sorted_src,
                                               const float* __restrict__ W,
                                               const float* __restrict__ b,
                                               float* __restrict__ out) {
    __shared__ float sW[F * F];
    __shared__ float srow[4][F];
    int t = threadIdx.x;
    for (int i = t; i < F * F; i += 256) sW[i] = W[i];
    int wid = t >> 6, lane = t & 63;
    int n = blockIdx.x * 4 + wid;
    int qe = lane >> 4, qc = lane & 15;
    float dn = dinv[n];
    int beg = offsets[n], end = offsets[n + 1];
    float4 acc = make_float4(0.f, 0.f, 0.f, 0.f);
    for (int base = beg; base < end; base += 4) {
        int e = base + qe;
        int s = n; float nm = 0.f;
        if (e < end) { s = sorted_src[e]; nm = dn * dinv[s]; }
        float4 v = reinterpret_cast<const float4*>(x + (size_t)s * F)[qc];
        acc.x = fmaf(nm, v.x, acc.x); acc.y = fmaf(nm, v.y, acc.y);
        acc.z = fmaf(nm, v.z, acc.z); acc.w = fmaf(nm, v.w, acc.w);
    }
    acc.x += __shfl_xor(acc.x, 16); acc.y += __shfl_xor(acc.y, 16);
    acc.z += __shfl_xor(acc.z, 16); acc.w += __shfl_xor(acc.w, 16);
    acc.x += __shfl_xor(acc.x, 32); acc.y += __shfl_xor(acc.y, 32);
    acc.z += __shfl_xor(acc.z, 32); acc.w += __shfl_xor(acc.w, 32);
    float c2 = 2.0f * dn * dn;
    float4 xv = reinterpret_cast<const float4*>(x + (size_t)n * F)[qc];
    acc.x = fmaf(c2, xv.x, acc.x); acc.y = fmaf(c2, xv.y, acc.y);
    acc.z = fmaf(c2, xv.z, acc.z); acc.w = fmaf(c2, xv.w, acc.w);
    if (qe == 0) reinterpret_cast<float4*>(&srow[wid][0])[qc] = acc;
    __syncthreads();
    float y = b[lane];
#pragma unroll
    for (int k = 0; k < F; ++k) y = fmaf(srow[wid][k], sW[k * F + lane], y);
    y = fmaxf(y, 0.0f);
    float m = y;
#pragma unroll
    for (int off = 32; off > 0; off >>= 1) m = fmaxf(m, __shfl_xor(m, off));
    float ex = __expf(y - m);
    float ss = ex;
#pragma unroll
    for (int off = 32; off > 0; off >>= 1) ss += __shfl_xor(ss, off);
    out[n * F + lane] = y - m - __logf(ss);
}

// ---------------- tier-C fallback (atomic scatter) --------------------------

__global__ void k_init_deg_f(float* __restrict__ deg) {
    int i = blockIdx.x * blockDim.x + threadIdx.x;
    if (i < N_NODES) deg[i] = 2.0f;
}
__global__ void k_count_f(const int* __restrict__ dst, float* __restrict__ deg) {
    int e = blockIdx.x * blockDim.x + threadIdx.x;
    if (e < N_EDGES) atomicAdd(&deg[dst[e]], 1.0f);
}
__global__ void k_dinv_f(float* __restrict__ deg) {
    int i = blockIdx.x * blockDim.x + threadIdx.x;
    if (i < N_NODES) deg[i] = rsqrtf(deg[i]);
}
__global__ void k_selfinit_f(const float* __restrict__ x, const float* __restrict__ dinv,
                             float* __restrict__ agg) {
    int t = blockIdx.x * blockDim.x + threadIdx.x;
    if (t >= N_NODES * (F / 4)) return;
    int n = t >> 4;
    float d = dinv[n];
    float c = 2.0f * d * d;
    float4 v = reinterpret_cast<const float4*>(x)[t];
    float4 o; o.x = c*v.x; o.y = c*v.y; o.z = c*v.z; o.w = c*v.w;
    reinterpret_cast<float4*>(agg)[t] = o;
}
__global__ __launch_bounds__(256) void k_scatter_f(const int* __restrict__ src,
                                                   const int* __restrict__ dst,
                                                   const float* __restrict__ x,
                                                   const float* __restrict__ dinv,
                                                   float* __restrict__ agg) {
    int wave = (blockIdx.x * blockDim.x + threadIdx.x) >> 6;
    int lane = threadIdx.x & 63;
    if (wave >= N_EDGES) return;
    int s = src[wave], d = dst[wave];
    atomicAdd(&agg[d * F + lane], dinv[s] * dinv[d] * x[s * F + lane]);
}
__global__ __launch_bounds__(256) void k_final_f(const float* __restrict__ W,
                                                 const float* __restrict__ b,
                                                 float* __restrict__ out) {
    __shared__ float sW[F * F];
    __shared__ float srow[4][F];
    int t = threadIdx.x;
    for (int i = t; i < F * F; i += 256) sW[i] = W[i];
    int wid = t >> 6, lane = t & 63;
    int n = blockIdx.x * 4 + wid;
    float rv = out[n * F + lane];
    srow[wid][lane] = rv;
    __syncthreads();
    float y = b[lane];
#pragma unroll
    for (int k = 0; k < F; ++k) y = fmaf(srow[wid][k], sW[k * F + lane], y);
    y = fmaxf(y, 0.0f);
    float m = y;
#pragma unroll
    for (int off = 32; off > 0; off >>= 1) m = fmaxf(m, __shfl_xor(m, off));
    float ex = __expf(y - m);
    float ss = ex;
#pragma unroll
    for (int off = 32; off > 0; off >>= 1) ss += __shfl_xor(ss, off);
    out[n * F + lane] = y - m - __logf(ss);
}

// ---------------------------------------------------------------------------

extern "C" void kernel_launch(void* const* d_in, const int* in_sizes, int n_in,
                              void* d_out, int out_size, void* d_ws, size_t ws_size,
                              hipStream_t stream) {
    const float* x    = (const float*)d_in[0];
    const int*   eidx = (const int*)d_in[1];   // [2][E]: row0 = src, row1 = dst
    const float* W    = (const float*)d_in[2];
    const float* b    = (const float*)d_in[3];
    const int* src = eidx;
    const int* dst = eidx + N_EDGES;
    float* out = (float*)d_out;

    // Tier-A3 ws layout (byte offsets):
    //   offsets      [0,        200064)   (50001 ints)
    //   dinv         [200064,   400128)
    //   bcnt         [400128,   401152)
    //   bbase        [401152,   402176)   (99 ints)
    //   bcur         [402176,   403200)
    //   pack (int)   [403200,   3603200)
    //   staging/xh   [3603200, 10003200)  (int2 / half, time-disjoint)
    const size_t NEED_A3 = 10003200;
    const size_t NEED_B  = 3801040;

    if (ws_size >= NEED_A3) {
        char* ws = (char*)d_ws;
        int*    offsets = (int*)(ws);
        float*  dinv    = (float*)(ws + 200064);
        int*    bcnt    = (int*)(ws + 400128);
        int*    bbase   = (int*)(ws + 401152);
        int*    bcur    = (int*)(ws + 402176);
        int*    pack    = (int*)(ws + 403200);
        int2*   staging = (int2*)(ws + 3603200);
        __half* xh      = (__half*)(ws + 3603200);

        hipMemsetAsync(bcnt, 0, 1024, stream);
        k_bcount<<<P1_BLOCKS, 1024, 0, stream>>>(dst, bcnt);
        k_bscan<<<1, 128, 0, stream>>>(bcnt, bbase, bcur, offsets);
        k_p1<<<P1_BLOCKS, 1024, 0, stream>>>(src, dst, bcur, staging);
        k_p23<<<NBUCK, 1024, 0, stream>>>(staging, bbase, offsets, dinv, pack);
        k_convert<<<N_NODES * (F / 4) / 256, 256, 0, stream>>>((const float4*)x, (uint2*)xh);
        k_agg<<<(N_NODES + NPB - 1) / NPB, 512, 0, stream>>>(
            x, xh, dinv, offsets, pack, W, b, out);
    } else if (ws_size >= NEED_B) {
        char* ws = (char*)d_ws;
        int*   counts     = (int*)(ws);
        int*   offsets    = (int*)(ws + 200000);
        float* dinv       = (float*)(ws + 400016);
        int*   bs         = (int*)(ws + 600016);
        int*   sorted_src = (int*)(ws + 601040);

        hipMemsetAsync(counts, 0, N_NODES * sizeof(int), stream);
        k_count_b<<<(N_EDGES + 255) / 256, 256, 0, stream>>>(dst, counts);
        k_blocksum<<<NB, 256, 0, stream>>>(counts, bs);
        k_scanblocks<<<1, 256, 0, stream>>>(bs);
        k_offsets_b<<<NB, 256, 0, stream>>>(counts, bs, offsets, dinv);
        k_fill_b<<<(N_EDGES + 255) / 256, 256, 0, stream>>>(src, dst, counts, sorted_src);
        k_agg_b<<<N_NODES / 4, 256, 0, stream>>>(x, dinv, offsets, sorted_src, W, b, out);
    } else {
        float* deg = (float*)d_ws;
        k_init_deg_f<<<(N_NODES + 255) / 256, 256, 0, stream>>>(deg);
        k_count_f<<<(N_EDGES + 255) / 256, 256, 0, stream>>>(dst, deg);
        k_dinv_f<<<(N_NODES + 255) / 256, 256, 0, stream>>>(deg);
        k_selfinit_f<<<(N_NODES * (F / 4) + 255) / 256, 256, 0, stream>>>(x, deg, out);
        k_scatter_f<<<(N_EDGES * 64 + 255) / 256, 256, 0, stream>>>(src, dst, x, deg, out);
        k_final_f<<<N_NODES / 4, 256, 0, stream>>>(W, b, out);
    }
}

// Round 7
// 95.738 us; speedup vs baseline: 3.6577x; 1.1552x over previous
//
#include <hip/hip_runtime.h>
#include <hip/hip_fp16.h>

#define N_NODES 50000
#define N_EDGES 800000
#define F 64
#define NB ((N_NODES + 255) / 256)   // tier-B node-scan blocks
#define NBUCK 98                      // buckets of 512 nodes (dst >> 9)
#define BSHIFT 9
#define BCAP 12288                    // fixed bucket capacity (mean 8163, sigma 90)
#define P1_BLOCKS ((N_EDGES + 1023) / 1024)   // 782
#define NPB 16                        // nodes per k_agg block (4 waves x 4)

// ---------------------------------------------------------------------------
// GCNConv improved=True. Pipeline (5 dispatches):
//   1) init:   bcur[b] = b*BCAP  (fixed-capacity buckets -> no histogram/scan)
//   2) p1:     bin edges into staging[bucket region], packed (dlocal<<16|src)
//   3) p23:    per-bucket: node histogram + in-LDS 512-scan -> offsets/counts/
//              dinv; then in-bucket counting scatter via LDS cursors -> pack
//   4) convert: xh = fp16(x)   (overlays dead staging)
//   5) agg:    4 waves x 4 nodes: preload pack+norm, shfl-distributed
//              independent fp16 row gathers, 4-node-interleaved GEMM from LDS,
//              relu, log_softmax.
// Aggregate x BEFORE the weight transform ((A x) W == A (x W)).
// src fits in 16 bits (50000 < 65536); in-bucket dst is 9 bits.
// ---------------------------------------------------------------------------

union H2U { __half2 h; unsigned u; };

// ---- step 1: bucket cursor init --------------------------------------------
__global__ void k_init(int* __restrict__ bcur) {
    int t = threadIdx.x;
    if (t < NBUCK) bcur[t] = t * BCAP;
}

// ---- step 2: bin edges into fixed-capacity bucket regions -------------------
__global__ __launch_bounds__(1024) void k_p1(const int* __restrict__ src,
                                             const int* __restrict__ dst,
                                             int* __restrict__ bcur,
                                             int* __restrict__ staging) {
    __shared__ int lcnt[NBUCK];
    __shared__ int lbase[NBUCK];
    int t = threadIdx.x;
    if (t < NBUCK) lcnt[t] = 0;
    __syncthreads();
    int e = blockIdx.x * 1024 + t;
    int s = 0, d = 0, bk = 0, rank = 0;
    bool valid = (e < N_EDGES);
    if (valid) {
        s = src[e]; d = dst[e];
        bk = d >> BSHIFT;
        rank = atomicAdd(&lcnt[bk], 1);       // LDS
    }
    __syncthreads();
    if (t < NBUCK && lcnt[t]) lbase[t] = atomicAdd(&bcur[t], lcnt[t]);
    __syncthreads();
    if (valid)
        staging[lbase[bk] + rank] = ((d & 511) << 16) | s;   // 4B grouped bursts
}

// ---- step 3: per-bucket histogram + LDS scan + counting scatter -------------
__global__ __launch_bounds__(1024) void k_p23(const int* __restrict__ staging,
                                              const int* __restrict__ bcur,
                                              int* __restrict__ offsets,
                                              int* __restrict__ counts,
                                              float* __restrict__ dinv,
                                              int* __restrict__ pack) {
    __shared__ int ncnt[512];
    __shared__ int lcur[512];
    int t = threadIdx.x;
    int b = blockIdx.x;
    int nb0 = b << BSHIFT;
    if (t < 512) ncnt[t] = 0;
    __syncthreads();
    int beg = b * BCAP, end = bcur[b];
    for (int i = beg + t; i < end; i += 1024)
        atomicAdd(&ncnt[staging[i] >> 16], 1);   // LDS
    __syncthreads();
    int c = (t < 512) ? ncnt[t] : 0;
    // inclusive Hillis-Steele scan of ncnt[0..511]
    for (int off = 1; off < 512; off <<= 1) {
        int u = (t < 512 && t >= off) ? ncnt[t - off] : 0;
        __syncthreads();
        if (t < 512) ncnt[t] += u;
        __syncthreads();
    }
    if (t < 512) {
        int goff = beg + (ncnt[t] - c);          // exclusive prefix + bucket base
        lcur[t] = goff;
        int node = nb0 + t;
        if (node < N_NODES) {
            offsets[node] = goff;
            counts[node]  = c;
            dinv[node]    = rsqrtf((float)c + 2.0f);
        }
    }
    __syncthreads();
    for (int i = beg + t; i < end; i += 1024) {
        int v = staging[i];                       // L2-hot re-read
        int pos = atomicAdd(&lcur[v >> 16], 1);   // LDS cursor
        pack[pos] = v & 0xFFFF;                   // src, 4B store, ~48KB window
    }
}

// ---- step 4: x -> fp16 (overlays dead staging) ------------------------------
__global__ __launch_bounds__(256) void k_convert(const float4* __restrict__ x4,
                                                 uint2* __restrict__ xh8) {
    int t = blockIdx.x * 256 + threadIdx.x;   // grid exactly N*F/4 = 800000
    float4 v = x4[t];
    H2U a, b;
    a.h = __float22half2_rn(make_float2(v.x, v.y));
    b.h = __float22half2_rn(make_float2(v.z, v.w));
    uint2 o; o.x = a.u; o.y = b.u;
    xh8[t] = o;
}

// ---- step 5: aggregate + GEMM + relu + log_softmax --------------------------
// 256 threads = 4 waves; wave handles 4 nodes. Edge phase: qe=lane>>4 picks
// 1 of 4 parallel edges, qc=lane&15 picks the 8B (4-half) slice of the 128B
// fp16 row; reduce = 2 shfl_xor per acc. GEMM: wave-private srows; sW[k][lane]
// read once, used for 4 rows.
__global__ __launch_bounds__(256) void k_agg(const float* __restrict__ x,
                                             const __half* __restrict__ xh,
                                             const float* __restrict__ dinv,
                                             const int* __restrict__ offsets,
                                             const int* __restrict__ counts,
                                             const int* __restrict__ pack,
                                             const float* __restrict__ W,
                                             const float* __restrict__ bias,
                                             float* __restrict__ out) {
    __shared__ float sW[F * F];
    __shared__ float srow[NPB][F];
    int t = threadIdx.x;
    {
        const float4* W4 = reinterpret_cast<const float4*>(W);
        float4* s4 = reinterpret_cast<float4*>(sW);
        for (int i = t; i < F * F / 4; i += 256) s4[i] = W4[i];
    }
    __syncthreads();

    int wid = t >> 6, lane = t & 63;
    int qe = lane >> 4, qc = lane & 15;
    int nbase = blockIdx.x * NPB + wid * 4;      // 3125*16 == 50000 exactly
    const uint2* xh8 = reinterpret_cast<const uint2*>(xh);

    // ---- preload phase: offsets, counts, dinv, pack entry + norm per lane ----
    int  begs[4], degs[4], pls[4];
    float dns[4], nms[4];
#pragma unroll
    for (int i = 0; i < 4; ++i) {
        int n = nbase + i;
        begs[i] = offsets[n];
        degs[i] = counts[n];
        dns[i]  = dinv[n];
    }
#pragma unroll
    for (int i = 0; i < 4; ++i) {
        int s = 0; float nm = 0.f;
        if (lane < degs[i]) {
            s = pack[begs[i] + lane];
            nm = dns[i] * dinv[s];
        }
        pls[i] = s; nms[i] = nm;
    }

    // ---- per-node aggregation ----
#pragma unroll
    for (int i = 0; i < 4; ++i) {
        int n = nbase + i;
        float a0 = 0.f, a1 = 0.f, a2 = 0.f, a3 = 0.f;
        int deg = degs[i];
        int lim = min(deg, 64);
        for (int r = 0; r < lim; r += 8) {        // 8 edges/iter, 2 indep loads
            int e0 = r + qe, e1 = r + 4 + qe;     // always <= 63
            int   s0 = __shfl(pls[i], e0);
            float m0 = __shfl(nms[i], e0);
            int   s1 = __shfl(pls[i], e1);
            float m1 = __shfl(nms[i], e1);
            uint2 r0 = xh8[(size_t)s0 * 16 + qc];
            uint2 r1 = xh8[(size_t)s1 * 16 + qc];
            H2U u0, u1; float2 f;
            u0.u = r0.x; u1.u = r0.y;
            f = __half22float2(u0.h); a0 = fmaf(m0, f.x, a0); a1 = fmaf(m0, f.y, a1);
            f = __half22float2(u1.h); a2 = fmaf(m0, f.x, a2); a3 = fmaf(m0, f.y, a3);
            u0.u = r1.x; u1.u = r1.y;
            f = __half22float2(u0.h); a0 = fmaf(m1, f.x, a0); a1 = fmaf(m1, f.y, a1);
            f = __half22float2(u1.h); a2 = fmaf(m1, f.x, a2); a3 = fmaf(m1, f.y, a3);
        }
        // ultra-rare overflow (deg > 64)
        int dend = begs[i] + deg;
        for (int base = begs[i] + 64; base < dend; base += 8) {
            int e0 = base + qe, e1 = base + 4 + qe;
            int s0 = 0, s1 = 0; float m0 = 0.f, m1 = 0.f;
            if (e0 < dend) { s0 = pack[e0]; m0 = dns[i] * dinv[s0]; }
            if (e1 < dend) { s1 = pack[e1]; m1 = dns[i] * dinv[s1]; }
            uint2 r0 = xh8[(size_t)s0 * 16 + qc];
            uint2 r1 = xh8[(size_t)s1 * 16 + qc];
            H2U u0, u1; float2 f;
            u0.u = r0.x; u1.u = r0.y;
            f = __half22float2(u0.h); a0 = fmaf(m0, f.x, a0); a1 = fmaf(m0, f.y, a1);
            f = __half22float2(u1.h); a2 = fmaf(m0, f.x, a2); a3 = fmaf(m0, f.y, a3);
            u0.u = r1.x; u1.u = r1.y;
            f = __half22float2(u0.h); a0 = fmaf(m1, f.x, a0); a1 = fmaf(m1, f.y, a1);
            f = __half22float2(u1.h); a2 = fmaf(m1, f.x, a2); a3 = fmaf(m1, f.y, a3);
        }
        // reduce across the 4 edge groups (lane bits 4,5)
        a0 += __shfl_xor(a0, 16); a0 += __shfl_xor(a0, 32);
        a1 += __shfl_xor(a1, 16); a1 += __shfl_xor(a1, 32);
        a2 += __shfl_xor(a2, 16); a2 += __shfl_xor(a2, 32);
        a3 += __shfl_xor(a3, 16); a3 += __shfl_xor(a3, 32);
        // self loop (weight 2), f32 x; write wave-private srow
        if (qe == 0) {
            float c2 = 2.0f * dns[i] * dns[i];
            float4 xv = reinterpret_cast<const float4*>(x + (size_t)n * F)[qc];
            a0 = fmaf(c2, xv.x, a0); a1 = fmaf(c2, xv.y, a1);
            a2 = fmaf(c2, xv.z, a2); a3 = fmaf(c2, xv.w, a3);
            float4 w; w.x = a0; w.y = a1; w.z = a2; w.w = a3;
            *reinterpret_cast<float4*>(&srow[wid * 4 + i][qc * 4]) = w;
        }
    }

    // wave-private srows: no barrier needed, just drain LDS writes
    asm volatile("s_waitcnt lgkmcnt(0)" ::: "memory");

    // ---- 4-node-interleaved GEMM: y[c] = sum_k srow[k] * W[k][c] ----
    float bl = bias[lane];
    float y0 = bl, y1 = bl, y2 = bl, y3 = bl;
#pragma unroll 4
    for (int j = 0; j < 16; ++j) {
        float4 r0 = *reinterpret_cast<const float4*>(&srow[wid * 4 + 0][j * 4]);
        float4 r1 = *reinterpret_cast<const float4*>(&srow[wid * 4 + 1][j * 4]);
        float4 r2 = *reinterpret_cast<const float4*>(&srow[wid * 4 + 2][j * 4]);
        float4 r3 = *reinterpret_cast<const float4*>(&srow[wid * 4 + 3][j * 4]);
        float w0 = sW[(4 * j + 0) * F + lane];
        float w1 = sW[(4 * j + 1) * F + lane];
        float w2 = sW[(4 * j + 2) * F + lane];
        float w3 = sW[(4 * j + 3) * F + lane];
        y0 = fmaf(r0.x, w0, y0); y0 = fmaf(r0.y, w1, y0); y0 = fmaf(r0.z, w2, y0); y0 = fmaf(r0.w, w3, y0);
        y1 = fmaf(r1.x, w0, y1); y1 = fmaf(r1.y, w1, y1); y1 = fmaf(r1.z, w2, y1); y1 = fmaf(r1.w, w3, y1);
        y2 = fmaf(r2.x, w0, y2); y2 = fmaf(r2.y, w1, y2); y2 = fmaf(r2.z, w2, y2); y2 = fmaf(r2.w, w3, y2);
        y3 = fmaf(r3.x, w0, y3); y3 = fmaf(r3.y, w1, y3); y3 = fmaf(r3.z, w2, y3); y3 = fmaf(r3.w, w3, y3);
    }

    float ys[4] = { y0, y1, y2, y3 };
#pragma unroll
    for (int i = 0; i < 4; ++i) {
        float y = fmaxf(ys[i], 0.0f);             // relu
        float mx = y;
#pragma unroll
        for (int off = 32; off > 0; off >>= 1)
            mx = fmaxf(mx, __shfl_xor(mx, off));
        float ex = __expf(y - mx);
        float ss = ex;
#pragma unroll
        for (int off = 32; off > 0; off >>= 1)
            ss += __shfl_xor(ss, off);
        out[(nbase + i) * F + lane] = y - mx - __logf(ss);
    }
}

// ---------------- tier-B fallback (round-3 f32 path) ------------------------

__global__ void k_count_b(const int* __restrict__ dst, int* __restrict__ counts) {
    int e = blockIdx.x * blockDim.x + threadIdx.x;
    if (e < N_EDGES) atomicAdd(&counts[dst[e]], 1);
}
__global__ __launch_bounds__(256) void k_blocksum(const int* __restrict__ counts,
                                                  int* __restrict__ bs) {
    __shared__ int sh[256];
    int t = threadIdx.x;
    int g = blockIdx.x * 256 + t;
    int v = (g < N_NODES) ? counts[g] : 0;
    sh[t] = v;
    __syncthreads();
    for (int off = 128; off > 0; off >>= 1) {
        if (t < off) sh[t] += sh[t + off];
        __syncthreads();
    }
    if (t == 0) bs[blockIdx.x] = sh[0];
}
__global__ __launch_bounds__(256) void k_scanblocks(int* __restrict__ bs) {
    __shared__ int sh[256];
    int t = threadIdx.x;
    int v = (t < NB) ? bs[t] : 0;
    sh[t] = v;
    __syncthreads();
    for (int off = 1; off < 256; off <<= 1) {
        int u = (t >= off) ? sh[t - off] : 0;
        __syncthreads();
        sh[t] += u;
        __syncthreads();
    }
    if (t < NB) bs[t] = sh[t] - v;
}
__global__ __launch_bounds__(256) void k_offsets_b(int* __restrict__ counts,
                                                   const int* __restrict__ bs,
                                                   int* __restrict__ offsets,
                                                   float* __restrict__ dinv) {
    __shared__ int sh[256];
    int t = threadIdx.x;
    int g = blockIdx.x * 256 + t;
    int c = (g < N_NODES) ? counts[g] : 0;
    sh[t] = c;
    __syncthreads();
    for (int off = 1; off < 256; off <<= 1) {
        int u = (t >= off) ? sh[t - off] : 0;
        __syncthreads();
        sh[t] += u;
        __syncthreads();
    }
    int excl = sh[t] - c + bs[blockIdx.x];
    if (g < N_NODES) {
        offsets[g] = excl;
        counts[g]  = excl;
        dinv[g]    = rsqrtf((float)c + 2.0f);
    }
    if (g == 0) offsets[N_NODES] = N_EDGES;
}
__global__ void k_fill_b(const int* __restrict__ src, const int* __restrict__ dst,
                         int* __restrict__ cursor, int* __restrict__ sorted_src) {
    int e = blockIdx.x * blockDim.x + threadIdx.x;
    if (e < N_EDGES) {
        int pos = atomicAdd(&cursor[dst[e]], 1);
        sorted_src[pos] = src[e];
    }
}
__global__ __launch_bounds__(256) void k_agg_b(const float* __restrict__ x,
                                               const float* __restrict__ dinv,
                                               const int* __restrict__ offsets,
                                               const int* __restrict__ sorted_src,
                                               const float* __restrict__ W,
                                               const float* __restrict__ b,
                                               float* __restrict__ out) {
    __shared__ float sW[F * F];
    __shared__ float srow[4][F];
    int t = threadIdx.x;
    for (int i = t; i < F * F; i += 256) sW[i] = W[i];
    int wid = t >> 6, lane = t & 63;
    int n = blockIdx.x * 4 + wid;
    int qe = lane >> 4, qc = lane & 15;
    float dn = dinv[n];
    int beg = offsets[n], end = offsets[n + 1];
    float4 acc = make_float4(0.f, 0.f, 0.f, 0.f);
    for (int base = beg; base < end; base += 4) {
        int e = base + qe;
        int s = n; float nm = 0.f;
        if (e < end) { s = sorted_src[e]; nm = dn * dinv[s]; }
        float4 v = reinterpret_cast<const float4*>(x + (size_t)s * F)[qc];
        acc.x = fmaf(nm, v.x, acc.x); acc.y = fmaf(nm, v.y, acc.y);
        acc.z = fmaf(nm, v.z, acc.z); acc.w = fmaf(nm, v.w, acc.w);
    }
    acc.x += __shfl_xor(acc.x, 16); acc.y += __shfl_xor(acc.y, 16);
    acc.z += __shfl_xor(acc.z, 16); acc.w += __shfl_xor(acc.w, 16);
    acc.x += __shfl_xor(acc.x, 32); acc.y += __shfl_xor(acc.y, 32);
    acc.z += __shfl_xor(acc.z, 32); acc.w += __shfl_xor(acc.w, 32);
    float c2 = 2.0f * dn * dn;
    float4 xv = reinterpret_cast<const float4*>(x + (size_t)n * F)[qc];
    acc.x = fmaf(c2, xv.x, acc.x); acc.y = fmaf(c2, xv.y, acc.y);
    acc.z = fmaf(c2, xv.z, acc.z); acc.w = fmaf(c2, xv.w, acc.w);
    if (qe == 0) reinterpret_cast<float4*>(&srow[wid][0])[qc] = acc;
    __syncthreads();
    float y = b[lane];
#pragma unroll
    for (int k = 0; k < F; ++k) y = fmaf(srow[wid][k], sW[k * F + lane], y);
    y = fmaxf(y, 0.0f);
    float m = y;
#pragma unroll
    for (int off = 32; off > 0; off >>= 1) m = fmaxf(m, __shfl_xor(m, off));
    float ex = __expf(y - m);
    float ss = ex;
#pragma unroll
    for (int off = 32; off > 0; off >>= 1) ss += __shfl_xor(ss, off);
    out[n * F + lane] = y - m - __logf(ss);
}

// ---------------- tier-C fallback (atomic scatter) --------------------------

__global__ void k_init_deg_f(float* __restrict__ deg) {
    int i = blockIdx.x * blockDim.x + threadIdx.x;
    if (i < N_NODES) deg[i] = 2.0f;
}
__global__ void k_count_f(const int* __restrict__ dst, float* __restrict__ deg) {
    int e = blockIdx.x * blockDim.x + threadIdx.x;
    if (e < N_EDGES) atomicAdd(&deg[dst[e]], 1.0f);
}
__global__ void k_dinv_f(float* __restrict__ deg) {
    int i = blockIdx.x * blockDim.x + threadIdx.x;
    if (i < N_NODES) deg[i] = rsqrtf(deg[i]);
}
__global__ void k_selfinit_f(const float* __restrict__ x, const float* __restrict__ dinv,
                             float* __restrict__ agg) {
    int t = blockIdx.x * blockDim.x + threadIdx.x;
    if (t >= N_NODES * (F / 4)) return;
    int n = t >> 4;
    float d = dinv[n];
    float c = 2.0f * d * d;
    float4 v = reinterpret_cast<const float4*>(x)[t];
    float4 o; o.x = c*v.x; o.y = c*v.y; o.z = c*v.z; o.w = c*v.w;
    reinterpret_cast<float4*>(agg)[t] = o;
}
__global__ __launch_bounds__(256) void k_scatter_f(const int* __restrict__ src,
                                                   const int* __restrict__ dst,
                                                   const float* __restrict__ x,
                                                   const float* __restrict__ dinv,
                                                   float* __restrict__ agg) {
    int wave = (blockIdx.x * blockDim.x + threadIdx.x) >> 6;
    int lane = threadIdx.x & 63;
    if (wave >= N_EDGES) return;
    int s = src[wave], d = dst[wave];
    atomicAdd(&agg[d * F + lane], dinv[s] * dinv[d] * x[s * F + lane]);
}
__global__ __launch_bounds__(256) void k_final_f(const float* __restrict__ W,
                                                 const float* __restrict__ b,
                                                 float* __restrict__ out) {
    __shared__ float sW[F * F];
    __shared__ float srow[4][F];
    int t = threadIdx.x;
    for (int i = t; i < F * F; i += 256) sW[i] = W[i];
    int wid = t >> 6, lane = t & 63;
    int n = blockIdx.x * 4 + wid;
    float rv = out[n * F + lane];
    srow[wid][lane] = rv;
    __syncthreads();
    float y = b[lane];
#pragma unroll
    for (int k = 0; k < F; ++k) y = fmaf(srow[wid][k], sW[k * F + lane], y);
    y = fmaxf(y, 0.0f);
    float m = y;
#pragma unroll
    for (int off = 32; off > 0; off >>= 1) m = fmaxf(m, __shfl_xor(m, off));
    float ex = __expf(y - m);
    float ss = ex;
#pragma unroll
    for (int off = 32; off > 0; off >>= 1) ss += __shfl_xor(ss, off);
    out[n * F + lane] = y - m - __logf(ss);
}

// ---------------------------------------------------------------------------

extern "C" void kernel_launch(void* const* d_in, const int* in_sizes, int n_in,
                              void* d_out, int out_size, void* d_ws, size_t ws_size,
                              hipStream_t stream) {
    const float* x    = (const float*)d_in[0];
    const int*   eidx = (const int*)d_in[1];   // [2][E]: row0 = src, row1 = dst
    const float* W    = (const float*)d_in[2];
    const float* b    = (const float*)d_in[3];
    const int* src = eidx;
    const int* dst = eidx + N_EDGES;
    float* out = (float*)d_out;

    // Tier-A4 ws layout (byte offsets):
    //   offsets      [0,        200064)
    //   counts       [200064,   400128)
    //   dinv         [400128,   600192)
    //   bcur         [600192,   601216)
    //   pack  (int)  [601216,   5418112)   (98 * 12288 * 4)
    //   staging/xh   [5418112, 11818112)   (int / half, time-disjoint)
    const size_t NEED_A4 = 11818112;
    const size_t NEED_B  = 3801040;

    if (ws_size >= NEED_A4) {
        char* ws = (char*)d_ws;
        int*    offsets = (int*)(ws);
        int*    counts  = (int*)(ws + 200064);
        float*  dinv    = (float*)(ws + 400128);
        int*    bcur    = (int*)(ws + 600192);
        int*    pack    = (int*)(ws + 601216);
        int*    staging = (int*)(ws + 5418112);
        __half* xh      = (__half*)(ws + 5418112);

        k_init<<<1, 128, 0, stream>>>(bcur);
        k_p1<<<P1_BLOCKS, 1024, 0, stream>>>(src, dst, bcur, staging);
        k_p23<<<NBUCK, 1024, 0, stream>>>(staging, bcur, offsets, counts, dinv, pack);
        k_convert<<<N_NODES * (F / 4) / 256, 256, 0, stream>>>((const float4*)x, (uint2*)xh);
        k_agg<<<N_NODES / NPB, 256, 0, stream>>>(
            x, xh, dinv, offsets, counts, pack, W, b, out);
    } else if (ws_size >= NEED_B) {
        char* ws = (char*)d_ws;
        int*   counts     = (int*)(ws);
        int*   offsets    = (int*)(ws + 200000);
        float* dinv       = (float*)(ws + 400016);
        int*   bs         = (int*)(ws + 600016);
        int*   sorted_src = (int*)(ws + 601040);

        hipMemsetAsync(counts, 0, N_NODES * sizeof(int), stream);
        k_count_b<<<(N_EDGES + 255) / 256, 256, 0, stream>>>(dst, counts);
        k_blocksum<<<NB, 256, 0, stream>>>(counts, bs);
        k_scanblocks<<<1, 256, 0, stream>>>(bs);
        k_offsets_b<<<NB, 256, 0, stream>>>(counts, bs, offsets, dinv);
        k_fill_b<<<(N_EDGES + 255) / 256, 256, 0, stream>>>(src, dst, counts, sorted_src);
        k_agg_b<<<N_NODES / 4, 256, 0, stream>>>(x, dinv, offsets, sorted_src, W, b, out);
    } else {
        float* deg = (float*)d_ws;
        k_init_deg_f<<<(N_NODES + 255) / 256, 256, 0, stream>>>(deg);
        k_count_f<<<(N_EDGES + 255) / 256, 256, 0, stream>>>(dst, deg);
        k_dinv_f<<<(N_NODES + 255) / 256, 256, 0, stream>>>(deg);
        k_selfinit_f<<<(N_NODES * (F / 4) + 255) / 256, 256, 0, stream>>>(x, deg, out);
        k_scatter_f<<<(N_EDGES * 64 + 255) / 256, 256, 0, stream>>>(src, dst, x, deg, out);
        k_final_f<<<N_NODES / 4, 256, 0, stream>>>(W, b, out);
    }
}

// Round 8
// 86.705 us; speedup vs baseline: 4.0388x; 1.1042x over previous
//
#include <hip/hip_runtime.h>
#include <hip/hip_fp16.h>

#define N_NODES 50000
#define N_EDGES 800000
#define F 64
#define NB ((N_NODES + 255) / 256)   // tier-B node-scan blocks
#define NBUCK 98                      // buckets of 512 nodes (dst >> 9)
#define BSHIFT 9
#define BCAP 12288                    // fixed bucket capacity (mean 8163, sigma 90)
#define P1_BLOCKS ((N_EDGES + 1023) / 1024)   // 782
#define NPB 32                        // nodes per k_agg block (8 waves x 4)

// ---------------------------------------------------------------------------
// GCNConv improved=True. Pipeline (5 dispatches):
//   1) init:   bcur[b] = b*BCAP  (fixed-capacity buckets -> no histogram/scan)
//   2) p1:     bin edges into staging[bucket region], packed (dlocal<<16|src)
//   3) p23:    per-bucket: node histogram + in-LDS 512-scan -> offsets/counts/
//              dinv; then in-bucket counting scatter via LDS cursors -> pack
//   4) convert: xh = fp16(x)   (overlays dead staging)
//   5) agg:    8 waves x 4 nodes; PAIRWISE-interleaved edge gathers (4 loads
//              in flight), fp16-packed sW (8KB), 4-node GEMM from LDS,
//              relu, log_softmax.
// Aggregate x BEFORE the weight transform ((A x) W == A (x W)).
// ---------------------------------------------------------------------------

union H2U { __half2 h; unsigned u; };

// ---- step 1: bucket cursor init --------------------------------------------
__global__ void k_init(int* __restrict__ bcur) {
    int t = threadIdx.x;
    if (t < NBUCK) bcur[t] = t * BCAP;
}

// ---- step 2: bin edges into fixed-capacity bucket regions -------------------
__global__ __launch_bounds__(1024) void k_p1(const int* __restrict__ src,
                                             const int* __restrict__ dst,
                                             int* __restrict__ bcur,
                                             int* __restrict__ staging) {
    __shared__ int lcnt[NBUCK];
    __shared__ int lbase[NBUCK];
    int t = threadIdx.x;
    if (t < NBUCK) lcnt[t] = 0;
    __syncthreads();
    int e = blockIdx.x * 1024 + t;
    int s = 0, d = 0, bk = 0, rank = 0;
    bool valid = (e < N_EDGES);
    if (valid) {
        s = src[e]; d = dst[e];
        bk = d >> BSHIFT;
        rank = atomicAdd(&lcnt[bk], 1);       // LDS
    }
    __syncthreads();
    if (t < NBUCK && lcnt[t]) lbase[t] = atomicAdd(&bcur[t], lcnt[t]);
    __syncthreads();
    if (valid)
        staging[lbase[bk] + rank] = ((d & 511) << 16) | s;   // 4B grouped bursts
}

// ---- step 3: per-bucket histogram + LDS scan + counting scatter -------------
__global__ __launch_bounds__(1024) void k_p23(const int* __restrict__ staging,
                                              const int* __restrict__ bcur,
                                              int* __restrict__ offsets,
                                              int* __restrict__ counts,
                                              float* __restrict__ dinv,
                                              int* __restrict__ pack) {
    __shared__ int ncnt[512];
    __shared__ int lcur[512];
    int t = threadIdx.x;
    int b = blockIdx.x;
    int nb0 = b << BSHIFT;
    if (t < 512) ncnt[t] = 0;
    __syncthreads();
    int beg = b * BCAP, end = bcur[b];
    for (int i = beg + t; i < end; i += 1024)
        atomicAdd(&ncnt[staging[i] >> 16], 1);   // LDS
    __syncthreads();
    int c = (t < 512) ? ncnt[t] : 0;
    // inclusive Hillis-Steele scan of ncnt[0..511]
    for (int off = 1; off < 512; off <<= 1) {
        int u = (t < 512 && t >= off) ? ncnt[t - off] : 0;
        __syncthreads();
        if (t < 512) ncnt[t] += u;
        __syncthreads();
    }
    if (t < 512) {
        int goff = beg + (ncnt[t] - c);          // exclusive prefix + bucket base
        lcur[t] = goff;
        int node = nb0 + t;
        if (node < N_NODES) {
            offsets[node] = goff;
            counts[node]  = c;
            dinv[node]    = rsqrtf((float)c + 2.0f);
        }
    }
    __syncthreads();
    for (int i = beg + t; i < end; i += 1024) {
        int v = staging[i];                       // L2-hot re-read
        int pos = atomicAdd(&lcur[v >> 16], 1);   // LDS cursor
        pack[pos] = v & 0xFFFF;                   // src, 4B store, ~48KB window
    }
}

// ---- step 4: x -> fp16 (overlays dead staging) ------------------------------
__global__ __launch_bounds__(256) void k_convert(const float4* __restrict__ x4,
                                                 uint2* __restrict__ xh8) {
    int t = blockIdx.x * 256 + threadIdx.x;   // grid exactly N*F/4 = 800000
    float4 v = x4[t];
    H2U a, b;
    a.h = __float22half2_rn(make_float2(v.x, v.y));
    b.h = __float22half2_rn(make_float2(v.z, v.w));
    uint2 o; o.x = a.u; o.y = b.u;
    xh8[t] = o;
}

// ---- step 5: aggregate + GEMM + relu + log_softmax --------------------------
// 512 threads = 8 waves; wave handles 4 nodes, processed as 2 interleaved
// pairs (4 independent row gathers in flight). qe=lane>>4 picks 1 of 4
// parallel edges, qc=lane&15 picks the 8B slice of the 128B fp16 row.
// Lanes >= deg carry nm=0 from preload -> unified pair loop needs no
// predication. GEMM: fp16-packed sW; sW reads shared across 4 rows.
__global__ __launch_bounds__(512) void k_agg(const float* __restrict__ x,
                                             const __half* __restrict__ xh,
                                             const float* __restrict__ dinv,
                                             const int* __restrict__ offsets,
                                             const int* __restrict__ counts,
                                             const int* __restrict__ pack,
                                             const float* __restrict__ W,
                                             const float* __restrict__ bias,
                                             float* __restrict__ out) {
    __shared__ unsigned sWu[F * F / 2];          // pair p -> {W[2p][c], W[2p+1][c]}
    __shared__ float srow[NPB][F];
    int t = threadIdx.x;
    for (int i = t; i < F * F / 2; i += 512) {   // 4 iters: pack W to fp16 pairs
        int p = i >> 6, c = i & 63;
        H2U u;
        u.h = __float22half2_rn(make_float2(W[(2 * p) * F + c], W[(2 * p + 1) * F + c]));
        sWu[i] = u.u;
    }
    __syncthreads();

    int wid = t >> 6, lane = t & 63;
    int qe = lane >> 4, qc = lane & 15;
    int nbase = blockIdx.x * NPB + wid * 4;      // grid 1563; tail guarded
    const uint2* xh8 = reinterpret_cast<const uint2*>(xh);

    // ---- preload: offsets/counts/dinv + one pack entry & norm per lane ----
    int  begs[4], degs[4], pls[4];
    float dns[4], nms[4];
#pragma unroll
    for (int i = 0; i < 4; ++i) {
        int n = nbase + i;
        if (n < N_NODES) {
            begs[i] = offsets[n]; degs[i] = counts[n]; dns[i] = dinv[n];
        } else { begs[i] = 0; degs[i] = 0; dns[i] = 0.f; }
    }
#pragma unroll
    for (int i = 0; i < 4; ++i) {
        int s = 0; float nm = 0.f;
        if (lane < degs[i]) {
            s = pack[begs[i] + lane];
            nm = dns[i] * dinv[s];
        }
        pls[i] = s; nms[i] = nm;
    }

    // ---- pairwise-interleaved aggregation ----
#pragma unroll
    for (int i = 0; i < 4; i += 2) {
        float a00 = 0.f, a01 = 0.f, a02 = 0.f, a03 = 0.f;   // node i
        float a10 = 0.f, a11 = 0.f, a12 = 0.f, a13 = 0.f;   // node i+1
        int lim = min(max(degs[i], degs[i + 1]), 64);
        for (int r = 0; r < lim; r += 8) {
            int e0 = r + qe, e1 = r + 4 + qe;               // <= 63 always
            int   s00 = __shfl(pls[i], e0);     float m00 = __shfl(nms[i], e0);
            int   s01 = __shfl(pls[i], e1);     float m01 = __shfl(nms[i], e1);
            int   s10 = __shfl(pls[i + 1], e0); float m10 = __shfl(nms[i + 1], e0);
            int   s11 = __shfl(pls[i + 1], e1); float m11 = __shfl(nms[i + 1], e1);
            uint2 v00 = xh8[(size_t)s00 * 16 + qc];         // 4 indep gathers
            uint2 v01 = xh8[(size_t)s01 * 16 + qc];
            uint2 v10 = xh8[(size_t)s10 * 16 + qc];
            uint2 v11 = xh8[(size_t)s11 * 16 + qc];
            H2U u0, u1; float2 f;
            u0.u = v00.x; u1.u = v00.y;
            f = __half22float2(u0.h); a00 = fmaf(m00, f.x, a00); a01 = fmaf(m00, f.y, a01);
            f = __half22float2(u1.h); a02 = fmaf(m00, f.x, a02); a03 = fmaf(m00, f.y, a03);
            u0.u = v01.x; u1.u = v01.y;
            f = __half22float2(u0.h); a00 = fmaf(m01, f.x, a00); a01 = fmaf(m01, f.y, a01);
            f = __half22float2(u1.h); a02 = fmaf(m01, f.x, a02); a03 = fmaf(m01, f.y, a03);
            u0.u = v10.x; u1.u = v10.y;
            f = __half22float2(u0.h); a10 = fmaf(m10, f.x, a10); a11 = fmaf(m10, f.y, a11);
            f = __half22float2(u1.h); a12 = fmaf(m10, f.x, a12); a13 = fmaf(m10, f.y, a13);
            u0.u = v11.x; u1.u = v11.y;
            f = __half22float2(u0.h); a10 = fmaf(m11, f.x, a10); a11 = fmaf(m11, f.y, a11);
            f = __half22float2(u1.h); a12 = fmaf(m11, f.x, a12); a13 = fmaf(m11, f.y, a13);
        }
        // ultra-rare overflow (deg > 64), per node, reads pack directly
#pragma unroll
        for (int k = 0; k < 2; ++k) {
            int dend = begs[i + k] + degs[i + k];
            for (int base = begs[i + k] + 64; base < dend; base += 8) {
                int e0 = base + qe, e1 = base + 4 + qe;
                int s0 = 0, s1 = 0; float m0 = 0.f, m1 = 0.f;
                if (e0 < dend) { s0 = pack[e0]; m0 = dns[i + k] * dinv[s0]; }
                if (e1 < dend) { s1 = pack[e1]; m1 = dns[i + k] * dinv[s1]; }
                uint2 r0 = xh8[(size_t)s0 * 16 + qc];
                uint2 r1 = xh8[(size_t)s1 * 16 + qc];
                H2U u0, u1; float2 f;
                float* A = (k == 0) ? &a00 : &a10;
                u0.u = r0.x; u1.u = r0.y;
                f = __half22float2(u0.h); A[0] = fmaf(m0, f.x, A[0]); A[1] = fmaf(m0, f.y, A[1]);
                f = __half22float2(u1.h); A[2] = fmaf(m0, f.x, A[2]); A[3] = fmaf(m0, f.y, A[3]);
                u0.u = r1.x; u1.u = r1.y;
                f = __half22float2(u0.h); A[0] = fmaf(m1, f.x, A[0]); A[1] = fmaf(m1, f.y, A[1]);
                f = __half22float2(u1.h); A[2] = fmaf(m1, f.x, A[2]); A[3] = fmaf(m1, f.y, A[3]);
            }
        }
        // reduce across 4 edge groups (two independent chains interleave)
        a00 += __shfl_xor(a00, 16); a10 += __shfl_xor(a10, 16);
        a01 += __shfl_xor(a01, 16); a11 += __shfl_xor(a11, 16);
        a02 += __shfl_xor(a02, 16); a12 += __shfl_xor(a12, 16);
        a03 += __shfl_xor(a03, 16); a13 += __shfl_xor(a13, 16);
        a00 += __shfl_xor(a00, 32); a10 += __shfl_xor(a10, 32);
        a01 += __shfl_xor(a01, 32); a11 += __shfl_xor(a11, 32);
        a02 += __shfl_xor(a02, 32); a12 += __shfl_xor(a12, 32);
        a03 += __shfl_xor(a03, 32); a13 += __shfl_xor(a13, 32);
        // self loop (weight 2) from f32 x, write wave-private srow
        if (qe == 0) {
            int n0 = nbase + i;
            if (n0 < N_NODES) {
                float c2 = 2.0f * dns[i] * dns[i];
                float4 xv = reinterpret_cast<const float4*>(x + (size_t)n0 * F)[qc];
                a00 = fmaf(c2, xv.x, a00); a01 = fmaf(c2, xv.y, a01);
                a02 = fmaf(c2, xv.z, a02); a03 = fmaf(c2, xv.w, a03);
                float4 w; w.x = a00; w.y = a01; w.z = a02; w.w = a03;
                *reinterpret_cast<float4*>(&srow[wid * 4 + i][qc * 4]) = w;
            }
            int n1 = nbase + i + 1;
            if (n1 < N_NODES) {
                float c2 = 2.0f * dns[i + 1] * dns[i + 1];
                float4 xv = reinterpret_cast<const float4*>(x + (size_t)n1 * F)[qc];
                a10 = fmaf(c2, xv.x, a10); a11 = fmaf(c2, xv.y, a11);
                a12 = fmaf(c2, xv.z, a12); a13 = fmaf(c2, xv.w, a13);
                float4 w; w.x = a10; w.y = a11; w.z = a12; w.w = a13;
                *reinterpret_cast<float4*>(&srow[wid * 4 + i + 1][qc * 4]) = w;
            }
        }
    }

    // wave-private srows: no barrier needed, just drain LDS writes
    asm volatile("s_waitcnt lgkmcnt(0)" ::: "memory");

    // ---- 4-node-interleaved GEMM: y[c] = sum_k srow[k] * W[k][c] ----
    float bl = bias[lane];
    float y0 = bl, y1 = bl, y2 = bl, y3 = bl;
#pragma unroll 4
    for (int j = 0; j < 16; ++j) {
        float4 r0 = *reinterpret_cast<const float4*>(&srow[wid * 4 + 0][j * 4]);
        float4 r1 = *reinterpret_cast<const float4*>(&srow[wid * 4 + 1][j * 4]);
        float4 r2 = *reinterpret_cast<const float4*>(&srow[wid * 4 + 2][j * 4]);
        float4 r3 = *reinterpret_cast<const float4*>(&srow[wid * 4 + 3][j * 4]);
        H2U ua, ub;
        ua.u = sWu[(2 * j) * F + lane];
        ub.u = sWu[(2 * j + 1) * F + lane];
        float2 wab = __half22float2(ua.h);    // W[4j][lane], W[4j+1][lane]
        float2 wcd = __half22float2(ub.h);    // W[4j+2][lane], W[4j+3][lane]
        y0 = fmaf(r0.x, wab.x, y0); y0 = fmaf(r0.y, wab.y, y0); y0 = fmaf(r0.z, wcd.x, y0); y0 = fmaf(r0.w, wcd.y, y0);
        y1 = fmaf(r1.x, wab.x, y1); y1 = fmaf(r1.y, wab.y, y1); y1 = fmaf(r1.z, wcd.x, y1); y1 = fmaf(r1.w, wcd.y, y1);
        y2 = fmaf(r2.x, wab.x, y2); y2 = fmaf(r2.y, wab.y, y2); y2 = fmaf(r2.z, wcd.x, y2); y2 = fmaf(r2.w, wcd.y, y2);
        y3 = fmaf(r3.x, wab.x, y3); y3 = fmaf(r3.y, wab.y, y3); y3 = fmaf(r3.z, wcd.x, y3); y3 = fmaf(r3.w, wcd.y, y3);
    }

    float ys[4] = { y0, y1, y2, y3 };
#pragma unroll
    for (int i = 0; i < 4; ++i) {
        float y = fmaxf(ys[i], 0.0f);             // relu
        float mx = y;
#pragma unroll
        for (int off = 32; off > 0; off >>= 1)
            mx = fmaxf(mx, __shfl_xor(mx, off));
        float ex = __expf(y - mx);
        float ss = ex;
#pragma unroll
        for (int off = 32; off > 0; off >>= 1)
            ss += __shfl_xor(ss, off);
        int n = nbase + i;
        if (n < N_NODES) out[n * F + lane] = y - mx - __logf(ss);
    }
}

// ---------------- tier-B fallback (round-3 f32 path) ------------------------

__global__ void k_count_b(const int* __restrict__ dst, int* __restrict__ counts) {
    int e = blockIdx.x * blockDim.x + threadIdx.x;
    if (e < N_EDGES) atomicAdd(&counts[dst[e]], 1);
}
__global__ __launch_bounds__(256) void k_blocksum(const int* __restrict__ counts,
                                                  int* __restrict__ bs) {
    __shared__ int sh[256];
    int t = threadIdx.x;
    int g = blockIdx.x * 256 + t;
    int v = (g < N_NODES) ? counts[g] : 0;
    sh[t] = v;
    __syncthreads();
    for (int off = 128; off > 0; off >>= 1) {
        if (t < off) sh[t] += sh[t + off];
        __syncthreads();
    }
    if (t == 0) bs[blockIdx.x] = sh[0];
}
__global__ __launch_bounds__(256) void k_scanblocks(int* __restrict__ bs) {
    __shared__ int sh[256];
    int t = threadIdx.x;
    int v = (t < NB) ? bs[t] : 0;
    sh[t] = v;
    __syncthreads();
    for (int off = 1; off < 256; off <<= 1) {
        int u = (t >= off) ? sh[t - off] : 0;
        __syncthreads();
        sh[t] += u;
        __syncthreads();
    }
    if (t < NB) bs[t] = sh[t] - v;
}
__global__ __launch_bounds__(256) void k_offsets_b(int* __restrict__ counts,
                                                   const int* __restrict__ bs,
                                                   int* __restrict__ offsets,
                                                   float* __restrict__ dinv) {
    __shared__ int sh[256];
    int t = threadIdx.x;
    int g = blockIdx.x * 256 + t;
    int c = (g < N_NODES) ? counts[g] : 0;
    sh[t] = c;
    __syncthreads();
    for (int off = 1; off < 256; off <<= 1) {
        int u = (t >= off) ? sh[t - off] : 0;
        __syncthreads();
        sh[t] += u;
        __syncthreads();
    }
    int excl = sh[t] - c + bs[blockIdx.x];
    if (g < N_NODES) {
        offsets[g] = excl;
        counts[g]  = excl;
        dinv[g]    = rsqrtf((float)c + 2.0f);
    }
    if (g == 0) offsets[N_NODES] = N_EDGES;
}
__global__ void k_fill_b(const int* __restrict__ src, const int* __restrict__ dst,
                         int* __restrict__ cursor, int* __restrict__ sorted_src) {
    int e = blockIdx.x * blockDim.x + threadIdx.x;
    if (e < N_EDGES) {
        int pos = atomicAdd(&cursor[dst[e]], 1);
        sorted_src[pos] = src[e];
    }
}
__global__ __launch_bounds__(256) void k_agg_b(const float* __restrict__ x,
                                               const float* __restrict__ dinv,
                                               const int* __restrict__ offsets,
                                               const int* __restrict__ sorted_src,
                                               const float* __restrict__ W,
                                               const float* __restrict__ b,
                                               float* __restrict__ out) {
    __shared__ float sW[F * F];
    __shared__ float srow[4][F];
    int t = threadIdx.x;
    for (int i = t; i < F * F; i += 256) sW[i] = W[i];
    int wid = t >> 6, lane = t & 63;
    int n = blockIdx.x * 4 + wid;
    int qe = lane >> 4, qc = lane & 15;
    float dn = dinv[n];
    int beg = offsets[n], end = offsets[n + 1];
    float4 acc = make_float4(0.f, 0.f, 0.f, 0.f);
    for (int base = beg; base < end; base += 4) {
        int e = base + qe;
        int s = n; float nm = 0.f;
        if (e < end) { s = sorted_src[e]; nm = dn * dinv[s]; }
        float4 v = reinterpret_cast<const float4*>(x + (size_t)s * F)[qc];
        acc.x = fmaf(nm, v.x, acc.x); acc.y = fmaf(nm, v.y, acc.y);
        acc.z = fmaf(nm, v.z, acc.z); acc.w = fmaf(nm, v.w, acc.w);
    }
    acc.x += __shfl_xor(acc.x, 16); acc.y += __shfl_xor(acc.y, 16);
    acc.z += __shfl_xor(acc.z, 16); acc.w += __shfl_xor(acc.w, 16);
    acc.x += __shfl_xor(acc.x, 32); acc.y += __shfl_xor(acc.y, 32);
    acc.z += __shfl_xor(acc.z, 32); acc.w += __shfl_xor(acc.w, 32);
    float c2 = 2.0f * dn * dn;
    float4 xv = reinterpret_cast<const float4*>(x + (size_t)n * F)[qc];
    acc.x = fmaf(c2, xv.x, acc.x); acc.y = fmaf(c2, xv.y, acc.y);
    acc.z = fmaf(c2, xv.z, acc.z); acc.w = fmaf(c2, xv.w, acc.w);
    if (qe == 0) reinterpret_cast<float4*>(&srow[wid][0])[qc] = acc;
    __syncthreads();
    float y = b[lane];
#pragma unroll
    for (int k = 0; k < F; ++k) y = fmaf(srow[wid][k], sW[k * F + lane], y);
    y = fmaxf(y, 0.0f);
    float m = y;
#pragma unroll
    for (int off = 32; off > 0; off >>= 1) m = fmaxf(m, __shfl_xor(m, off));
    float ex = __expf(y - m);
    float ss = ex;
#pragma unroll
    for (int off = 32; off > 0; off >>= 1) ss += __shfl_xor(ss, off);
    out[n * F + lane] = y - m - __logf(ss);
}

// ---------------- tier-C fallback (atomic scatter) --------------------------

__global__ void k_init_deg_f(float* __restrict__ deg) {
    int i = blockIdx.x * blockDim.x + threadIdx.x;
    if (i < N_NODES) deg[i] = 2.0f;
}
__global__ void k_count_f(const int* __restrict__ dst, float* __restrict__ deg) {
    int e = blockIdx.x * blockDim.x + threadIdx.x;
    if (e < N_EDGES) atomicAdd(&deg[dst[e]], 1.0f);
}
__global__ void k_dinv_f(float* __restrict__ deg) {
    int i = blockIdx.x * blockDim.x + threadIdx.x;
    if (i < N_NODES) deg[i] = rsqrtf(deg[i]);
}
__global__ void k_selfinit_f(const float* __restrict__ x, const float* __restrict__ dinv,
                             float* __restrict__ agg) {
    int t = blockIdx.x * blockDim.x + threadIdx.x;
    if (t >= N_NODES * (F / 4)) return;
    int n = t >> 4;
    float d = dinv[n];
    float c = 2.0f * d * d;
    float4 v = reinterpret_cast<const float4*>(x)[t];
    float4 o; o.x = c*v.x; o.y = c*v.y; o.z = c*v.z; o.w = c*v.w;
    reinterpret_cast<float4*>(agg)[t] = o;
}
__global__ __launch_bounds__(256) void k_scatter_f(const int* __restrict__ src,
                                                   const int* __restrict__ dst,
                                                   const float* __restrict__ x,
                                                   const float* __restrict__ dinv,
                                                   float* __restrict__ agg) {
    int wave = (blockIdx.x * blockDim.x + threadIdx.x) >> 6;
    int lane = threadIdx.x & 63;
    if (wave >= N_EDGES) return;
    int s = src[wave], d = dst[wave];
    atomicAdd(&agg[d * F + lane], dinv[s] * dinv[d] * x[s * F + lane]);
}
__global__ __launch_bounds__(256) void k_final_f(const float* __restrict__ W,
                                                 const float* __restrict__ b,
                                                 float* __restrict__ out) {
    __shared__ float sW[F * F];
    __shared__ float srow[4][F];
    int t = threadIdx.x;
    for (int i = t; i < F * F; i += 256) sW[i] = W[i];
    int wid = t >> 6, lane = t & 63;
    int n = blockIdx.x * 4 + wid;
    float rv = out[n * F + lane];
    srow[wid][lane] = rv;
    __syncthreads();
    float y = b[lane];
#pragma unroll
    for (int k = 0; k < F; ++k) y = fmaf(srow[wid][k], sW[k * F + lane], y);
    y = fmaxf(y, 0.0f);
    float m = y;
#pragma unroll
    for (int off = 32; off > 0; off >>= 1) m = fmaxf(m, __shfl_xor(m, off));
    float ex = __expf(y - m);
    float ss = ex;
#pragma unroll
    for (int off = 32; off > 0; off >>= 1) ss += __shfl_xor(ss, off);
    out[n * F + lane] = y - m - __logf(ss);
}

// ---------------------------------------------------------------------------

extern "C" void kernel_launch(void* const* d_in, const int* in_sizes, int n_in,
                              void* d_out, int out_size, void* d_ws, size_t ws_size,
                              hipStream_t stream) {
    const float* x    = (const float*)d_in[0];
    const int*   eidx = (const int*)d_in[1];   // [2][E]: row0 = src, row1 = dst
    const float* W    = (const float*)d_in[2];
    const float* b    = (const float*)d_in[3];
    const int* src = eidx;
    const int* dst = eidx + N_EDGES;
    float* out = (float*)d_out;

    // Tier-A4 ws layout (byte offsets):
    //   offsets      [0,        200064)
    //   counts       [200064,   400128)
    //   dinv         [400128,   600192)
    //   bcur         [600192,   601216)
    //   pack  (int)  [601216,   5418112)   (98 * 12288 * 4)
    //   staging/xh   [5418112, 11818112)   (int / half, time-disjoint)
    const size_t NEED_A4 = 11818112;
    const size_t NEED_B  = 3801040;

    if (ws_size >= NEED_A4) {
        char* ws = (char*)d_ws;
        int*    offsets = (int*)(ws);
        int*    counts  = (int*)(ws + 200064);
        float*  dinv    = (float*)(ws + 400128);
        int*    bcur    = (int*)(ws + 600192);
        int*    pack    = (int*)(ws + 601216);
        int*    staging = (int*)(ws + 5418112);
        __half* xh      = (__half*)(ws + 5418112);

        k_init<<<1, 128, 0, stream>>>(bcur);
        k_p1<<<P1_BLOCKS, 1024, 0, stream>>>(src, dst, bcur, staging);
        k_p23<<<NBUCK, 1024, 0, stream>>>(staging, bcur, offsets, counts, dinv, pack);
        k_convert<<<N_NODES * (F / 4) / 256, 256, 0, stream>>>((const float4*)x, (uint2*)xh);
        k_agg<<<(N_NODES + NPB - 1) / NPB, 512, 0, stream>>>(
            x, xh, dinv, offsets, counts, pack, W, b, out);
    } else if (ws_size >= NEED_B) {
        char* ws = (char*)d_ws;
        int*   counts     = (int*)(ws);
        int*   offsets    = (int*)(ws + 200000);
        float* dinv       = (float*)(ws + 400016);
        int*   bs         = (int*)(ws + 600016);
        int*   sorted_src = (int*)(ws + 601040);

        hipMemsetAsync(counts, 0, N_NODES * sizeof(int), stream);
        k_count_b<<<(N_EDGES + 255) / 256, 256, 0, stream>>>(dst, counts);
        k_blocksum<<<NB, 256, 0, stream>>>(counts, bs);
        k_scanblocks<<<1, 256, 0, stream>>>(bs);
        k_offsets_b<<<NB, 256, 0, stream>>>(counts, bs, offsets, dinv);
        k_fill_b<<<(N_EDGES + 255) / 256, 256, 0, stream>>>(src, dst, counts, sorted_src);
        k_agg_b<<<N_NODES / 4, 256, 0, stream>>>(x, dinv, offsets, sorted_src, W, b, out);
    } else {
        float* deg = (float*)d_ws;
        k_init_deg_f<<<(N_NODES + 255) / 256, 256, 0, stream>>>(deg);
        k_count_f<<<(N_EDGES + 255) / 256, 256, 0, stream>>>(dst, deg);
        k_dinv_f<<<(N_NODES + 255) / 256, 256, 0, stream>>>(deg);
        k_selfinit_f<<<(N_NODES * (F / 4) + 255) / 256, 256, 0, stream>>>(x, deg, out);
        k_scatter_f<<<(N_EDGES * 64 + 255) / 256, 256, 0, stream>>>(src, dst, x, deg, out);
        k_final_f<<<N_NODES / 4, 256, 0, stream>>>(W, b, out);
    }
}